// Round 4
// baseline (652.275 us; speedup 1.0000x reference)
//
#include <hip/hip_runtime.h>
#include <hip/hip_bf16.h>

#define NN 100000
#define EE 1600000
#define HID 128
#define CLS 40
#define EPSBN 1e-5f
#define NBUK ((NN + 255) >> 8)   // 391 coarse buckets of 256 nodes

typedef float f32x4 __attribute__((ext_vector_type(4)));
typedef short s16x8 __attribute__((ext_vector_type(8)));
union U48 { uint4 u; s16x8 s; };

static __device__ __forceinline__ unsigned short f2bf(float f) {
    unsigned u = __float_as_uint(f);
    unsigned r = (u + 0x7fff + ((u >> 16) & 1)) >> 16;   // RNE
    return (unsigned short)r;
}
static __device__ __forceinline__ unsigned pack2(float a, float b) {
    return (unsigned)f2bf(a) | ((unsigned)f2bf(b) << 16);
}
static __device__ __forceinline__ float bflo(unsigned v) { return __uint_as_float(v << 16); }
static __device__ __forceinline__ float bfhi(unsigned v) { return __uint_as_float(v & 0xffff0000u); }

// ---------------- degree / CSR build ----------------

__global__ void init_counts(int* counts, int n) {
    int i = blockIdx.x * 256 + threadIdx.x;
    if (i < n) counts[i] = 0;
}

__global__ void edge_count(const int* __restrict__ dst, int* counts, int e) {
    int i = blockIdx.x * 256 + threadIdx.x;
    if (i < e) atomicAdd(&counts[dst[i]], 1);
}

__global__ void make_dinv(const int* __restrict__ counts, float* dinv, int n) {
    int i = blockIdx.x * 256 + threadIdx.x;
    if (i < n) dinv[i] = rsqrtf((float)(counts[i] + 1));   // +1 self loop
}

__global__ __launch_bounds__(1024) void scan1(int* counts, int* blocksums, int n) {
    __shared__ int tmp[1024];
    int tid = threadIdx.x;
    int gid = blockIdx.x * 1024 + tid;
    int v = (gid < n) ? counts[gid] : 0;
    tmp[tid] = v;
    __syncthreads();
    for (int off = 1; off < 1024; off <<= 1) {
        int t = (tid >= off) ? tmp[tid - off] : 0;
        __syncthreads();
        tmp[tid] += t;
        __syncthreads();
    }
    if (gid < n) counts[gid] = tmp[tid];
    if (tid == 1023) blocksums[blockIdx.x] = tmp[1023];
}

__global__ void scan2(int* blocksums, int nb) {
    __shared__ int tmp[128];
    int tid = threadIdx.x;
    int v = (tid < nb) ? blocksums[tid] : 0;
    tmp[tid] = v;
    __syncthreads();
    for (int off = 1; off < 128; off <<= 1) {
        int t = (tid >= off) ? tmp[tid - off] : 0;
        __syncthreads();
        tmp[tid] += t;
        __syncthreads();
    }
    if (tid < nb) blocksums[tid] = (tid == 0) ? 0 : tmp[tid - 1];
}

__global__ void scan3(const int* __restrict__ incl, const int* __restrict__ blocksums,
                      int* row_ptr, int* cursor, int n) {
    int gid = blockIdx.x * 256 + threadIdx.x;
    if (gid >= n) return;
    int inc = incl[gid] + blocksums[gid >> 10];
    row_ptr[gid + 1] = inc;
    int start = (gid == 0) ? 0 : incl[gid - 1] + blocksums[(gid - 1) >> 10];
    cursor[gid] = start;
    if (gid == 0) row_ptr[0] = 0;
}

// bucket cursors: one per 256-node range, padded to 1 line (16 ints) each
__global__ void init_bcur(const int* __restrict__ row_ptr, int* bcur) {
    int b = blockIdx.x * 256 + threadIdx.x;
    if (b < NBUK) bcur[b * 16] = row_ptr[b << 8];
}

// phase 1: scatter edge into its dst bucket's region (write frontier = 391 hot lines)
__global__ void fill_p1(const int* __restrict__ src, const int* __restrict__ dst,
                        int* bcur, int* __restrict__ tmp, int e) {
    int i = blockIdx.x * 256 + threadIdx.x;
    if (i >= e) return;
    int s = src[i], d = dst[i];
    int p = atomicAdd(&bcur[(d >> 8) * 16], 1);
    tmp[p] = (s << 8) | (d & 255);          // s < 2^17, fits
}

// phase 2: one block per bucket; re-scatter within the L2-hot ~32KB window
__global__ __launch_bounds__(256) void fill_p2(const int* __restrict__ tmp,
                                               const int* __restrict__ row_ptr,
                                               const float* __restrict__ dinv,
                                               int* cursor, int2* __restrict__ csr) {
    int b = blockIdx.x;
    int lo = row_ptr[b << 8];
    int hiN = (b + 1) << 8;
    int hi = row_ptr[hiN > NN ? NN : hiN];
    for (int idx = lo + threadIdx.x; idx < hi; idx += 256) {
        int v = tmp[idx];
        int s = ((unsigned)v) >> 8;
        int d = (b << 8) | (v & 255);
        int p = atomicAdd(&cursor[d], 1);
        csr[p] = make_int2(s, __float_as_int(dinv[s] * dinv[d]));
    }
}

// ---------------- W pre-pack into MFMA B-fragment layout ----------------

__global__ void prep_w128(const float* __restrict__ W, unsigned* __restrict__ Wf) {
    int t = blockIdx.x * 256 + threadIdx.x;   // < 8192
    int q = t & 3, lane = (t >> 2) & 63, f = t >> 8;
    int ks = f >> 3, ct = f & 7;
    int k = ks * 32 + ((lane >> 4) << 3) + q * 2;
    int col = ct * 16 + (lane & 15);
    Wf[t] = pack2(W[k * 128 + col], W[(k + 1) * 128 + col]);
}

__global__ void prep_w40(const float* __restrict__ W, unsigned* __restrict__ Wf) {
    int t = blockIdx.x * 256 + threadIdx.x;   // < 3072
    int q = t & 3, lane = (t >> 2) & 63, f = t >> 8;
    int ks = f / 3, ct = f - ks * 3;
    int k = ks * 32 + ((lane >> 4) << 3) + q * 2;
    int col = ct * 16 + (lane & 15);
    float v0 = (col < CLS) ? W[k * CLS + col] : 0.0f;
    float v1 = (col < CLS) ? W[(k + 1) * CLS + col] : 0.0f;
    Wf[t] = pack2(v0, v1);
}

// ---------------- MFMA GEMMs ----------------

template <int MODE>
__global__ __launch_bounds__(256) void gemm128_mfma(const float* __restrict__ X,
                                                    const unsigned* __restrict__ Wf,
                                                    const float* __restrict__ scsh,
                                                    const float* __restrict__ xres,
                                                    unsigned* __restrict__ Hb) {
    int t = threadIdx.x;
    int lane = t & 63, w = t >> 6;
    int wr = w >> 1, wc = w & 1;
    int row_base = blockIdx.x * 64 + wr * 32;

    s16x8 b[4][4];
    const uint4* Wv = (const uint4*)Wf;
#pragma unroll
    for (int ks = 0; ks < 4; ks++)
#pragma unroll
        for (int ct = 0; ct < 4; ct++) {
            int f = ks * 8 + wc * 4 + ct;
            U48 u; u.u = Wv[f * 64 + lane];
            b[ks][ct] = u.s;
        }

    f32x4 acc[2][4] = {};
    int lrow = lane & 15;
    int koff = (lane >> 4) << 3;

#pragma unroll
    for (int ks = 0; ks < 4; ks++) {
        int k0 = ks * 32 + koff;
        float sc[8], sh[8];
        if (MODE == 1) {
            float4 s0 = *(const float4*)&scsh[k0];
            float4 s1 = *(const float4*)&scsh[k0 + 4];
            float4 h0 = *(const float4*)&scsh[128 + k0];
            float4 h1 = *(const float4*)&scsh[128 + k0 + 4];
            sc[0]=s0.x; sc[1]=s0.y; sc[2]=s0.z; sc[3]=s0.w;
            sc[4]=s1.x; sc[5]=s1.y; sc[6]=s1.z; sc[7]=s1.w;
            sh[0]=h0.x; sh[1]=h0.y; sh[2]=h0.z; sh[3]=h0.w;
            sh[4]=h1.x; sh[5]=h1.y; sh[6]=h1.z; sh[7]=h1.w;
        }
#pragma unroll
        for (int rf = 0; rf < 2; rf++) {
            int row = row_base + rf * 16 + lrow;
            float v[8];
            if (row < NN) {
                float4 a0 = *(const float4*)&X[(size_t)row * 128 + k0];
                float4 a1 = *(const float4*)&X[(size_t)row * 128 + k0 + 4];
                v[0]=a0.x; v[1]=a0.y; v[2]=a0.z; v[3]=a0.w;
                v[4]=a1.x; v[5]=a1.y; v[6]=a1.z; v[7]=a1.w;
                if (MODE == 1) {
                    float4 r0 = *(const float4*)&xres[(size_t)row * 128 + k0];
                    float4 r1 = *(const float4*)&xres[(size_t)row * 128 + k0 + 4];
                    float rr[8] = {r0.x,r0.y,r0.z,r0.w,r1.x,r1.y,r1.z,r1.w};
#pragma unroll
                    for (int j = 0; j < 8; j++)
                        v[j] = fmaxf(fmaf(v[j], sc[j], sh[j]) + rr[j], 0.0f);
                }
            } else {
#pragma unroll
                for (int j = 0; j < 8; j++) v[j] = 0.0f;
            }
            U48 a;
            a.u = make_uint4(pack2(v[0], v[1]), pack2(v[2], v[3]),
                             pack2(v[4], v[5]), pack2(v[6], v[7]));
#pragma unroll
            for (int ct = 0; ct < 4; ct++)
                acc[rf][ct] = __builtin_amdgcn_mfma_f32_16x16x32_bf16(a.s, b[ks][ct], acc[rf][ct], 0, 0, 0);
        }
    }

    unsigned short* Hs = (unsigned short*)Hb;
#pragma unroll
    for (int rf = 0; rf < 2; rf++)
#pragma unroll
        for (int ct = 0; ct < 4; ct++) {
            int col = wc * 64 + ct * 16 + lrow;
            int rbase = row_base + rf * 16 + ((lane >> 4) << 2);
#pragma unroll
            for (int r = 0; r < 4; r++) {
                int row = rbase + r;
                if (row < NN) Hs[(size_t)row * 128 + col] = f2bf(acc[rf][ct][r]);
            }
        }
}

__global__ __launch_bounds__(256) void gemm40_mfma(const float* __restrict__ X,
                                                   const unsigned* __restrict__ Wf,
                                                   const float* __restrict__ scsh,
                                                   unsigned* __restrict__ H3) {
    int t = threadIdx.x;
    int lane = t & 63, w = t >> 6;
    int row_base = blockIdx.x * 64 + w * 16;

    s16x8 b[4][3];
    const uint4* Wv = (const uint4*)Wf;
#pragma unroll
    for (int ks = 0; ks < 4; ks++)
#pragma unroll
        for (int ct = 0; ct < 3; ct++) {
            U48 u; u.u = Wv[(ks * 3 + ct) * 64 + lane];
            b[ks][ct] = u.s;
        }

    f32x4 acc[3] = {};
    int lrow = lane & 15;
    int koff = (lane >> 4) << 3;

#pragma unroll
    for (int ks = 0; ks < 4; ks++) {
        int k0 = ks * 32 + koff;
        float4 s0 = *(const float4*)&scsh[k0];
        float4 s1 = *(const float4*)&scsh[k0 + 4];
        float4 h0 = *(const float4*)&scsh[128 + k0];
        float4 h1 = *(const float4*)&scsh[128 + k0 + 4];
        float sc[8] = {s0.x,s0.y,s0.z,s0.w,s1.x,s1.y,s1.z,s1.w};
        float sh[8] = {h0.x,h0.y,h0.z,h0.w,h1.x,h1.y,h1.z,h1.w};
        int row = row_base + lrow;
        float v[8];
        if (row < NN) {
            float4 a0 = *(const float4*)&X[(size_t)row * 128 + k0];
            float4 a1 = *(const float4*)&X[(size_t)row * 128 + k0 + 4];
            float av[8] = {a0.x,a0.y,a0.z,a0.w,a1.x,a1.y,a1.z,a1.w};
#pragma unroll
            for (int j = 0; j < 8; j++)
                v[j] = fmaxf(fmaf(av[j], sc[j], sh[j]), 0.0f);
        } else {
#pragma unroll
            for (int j = 0; j < 8; j++) v[j] = 0.0f;
        }
        U48 a;
        a.u = make_uint4(pack2(v[0], v[1]), pack2(v[2], v[3]),
                         pack2(v[4], v[5]), pack2(v[6], v[7]));
#pragma unroll
        for (int ct = 0; ct < 3; ct++)
            acc[ct] = __builtin_amdgcn_mfma_f32_16x16x32_bf16(a.s, b[ks][ct], acc[ct], 0, 0, 0);
    }

    unsigned short* Hs = (unsigned short*)H3;
#pragma unroll
    for (int ct = 0; ct < 3; ct++) {
        int col = ct * 16 + lrow;
        if (col >= CLS) continue;
        int rbase = row_base + ((lane >> 4) << 2);
#pragma unroll
        for (int r = 0; r < 4; r++) {
            int row = rbase + r;
            if (row < NN) Hs[(size_t)row * CLS + col] = f2bf(acc[ct][r]);
        }
    }
}

// ---------------- aggregation (2 edges per wave) ----------------

// wave per node; lanes 0-31 edge e, lanes 32-63 edge e+1; uint2 = 4 features/lane
__global__ __launch_bounds__(256) void agg128_bf16(const uint2* __restrict__ h2,
                                                   const int* __restrict__ row_ptr,
                                                   const int2* __restrict__ csr,
                                                   const float* __restrict__ dinv,
                                                   const float* __restrict__ bias,
                                                   float* __restrict__ out) {
    int wid = threadIdx.x >> 6;
    int lane = threadIdx.x & 63;
    int half = lane >> 5, l32 = lane & 31;
    int node = blockIdx.x * 4 + wid;
    float di = dinv[node];
    float c0 = di * di;
    float a0 = 0.0f, a1 = 0.0f, a2 = 0.0f, a3 = 0.0f;
    if (half == 0) {
        uint2 v = h2[(size_t)node * 32 + l32];
        a0 = bflo(v.x) * c0; a1 = bfhi(v.x) * c0;
        a2 = bflo(v.y) * c0; a3 = bfhi(v.y) * c0;
    }
    int beg = row_ptr[node], end = row_ptr[node + 1];
    int e = beg;
    for (; e + 4 <= end; e += 4) {
        int2 p0 = csr[e + half];
        int2 p1 = csr[e + 2 + half];
        uint2 g0 = h2[(size_t)p0.x * 32 + l32];
        uint2 g1 = h2[(size_t)p1.x * 32 + l32];
        float q0 = __int_as_float(p0.y), q1 = __int_as_float(p1.y);
        a0 = fmaf(bflo(g0.x), q0, a0); a1 = fmaf(bfhi(g0.x), q0, a1);
        a2 = fmaf(bflo(g0.y), q0, a2); a3 = fmaf(bfhi(g0.y), q0, a3);
        a0 = fmaf(bflo(g1.x), q1, a0); a1 = fmaf(bfhi(g1.x), q1, a1);
        a2 = fmaf(bflo(g1.y), q1, a2); a3 = fmaf(bfhi(g1.y), q1, a3);
    }
    for (; e < end; e += 2) {
        int idx = e + half;
        if (idx < end) {
            int2 p = csr[idx];
            uint2 g = h2[(size_t)p.x * 32 + l32];
            float q = __int_as_float(p.y);
            a0 = fmaf(bflo(g.x), q, a0); a1 = fmaf(bfhi(g.x), q, a1);
            a2 = fmaf(bflo(g.y), q, a2); a3 = fmaf(bfhi(g.y), q, a3);
        }
    }
    a0 += __shfl_xor(a0, 32); a1 += __shfl_xor(a1, 32);
    a2 += __shfl_xor(a2, 32); a3 += __shfl_xor(a3, 32);
    if (half == 0) {
        float4 b = *(const float4*)&bias[l32 * 4];
        *(float4*)&out[(size_t)node * 128 + l32 * 4] =
            make_float4(a0 + b.x, a1 + b.y, a2 + b.z, a3 + b.w);
    }
}

// layer-3: 2 edges per wave (20 active lanes per half), fused log_softmax
__global__ __launch_bounds__(256) void agg40_lsm(const unsigned* __restrict__ h3,
                                                 const int* __restrict__ row_ptr,
                                                 const int2* __restrict__ csr,
                                                 const float* __restrict__ dinv,
                                                 const float* __restrict__ b3,
                                                 float* __restrict__ out) {
    int wid = threadIdx.x >> 6;
    int lane = threadIdx.x & 63;
    int half = lane >> 5, l32 = lane & 31;
    bool act = l32 < 20;
    int node = blockIdx.x * 4 + wid;
    float di = dinv[node];
    float c0 = di * di;
    float a0 = 0.0f, a1 = 0.0f;
    if (half == 0 && act) {
        unsigned v = h3[(size_t)node * 20 + l32];
        a0 = bflo(v) * c0;
        a1 = bfhi(v) * c0;
    }
    int beg = row_ptr[node], end = row_ptr[node + 1];
    int e = beg;
    for (; e + 4 <= end; e += 4) {
        int2 p0 = csr[e + half];
        int2 p1 = csr[e + 2 + half];
        unsigned g0 = act ? h3[(size_t)p0.x * 20 + l32] : 0u;
        unsigned g1 = act ? h3[(size_t)p1.x * 20 + l32] : 0u;
        float q0 = __int_as_float(p0.y), q1 = __int_as_float(p1.y);
        a0 = fmaf(bflo(g0), q0, a0); a1 = fmaf(bfhi(g0), q0, a1);
        a0 = fmaf(bflo(g1), q1, a0); a1 = fmaf(bfhi(g1), q1, a1);
    }
    for (; e < end; e += 2) {
        int idx = e + half;
        if (idx < end) {
            int2 p = csr[idx];
            unsigned g = act ? h3[(size_t)p.x * 20 + l32] : 0u;
            float q = __int_as_float(p.y);
            a0 = fmaf(bflo(g), q, a0);
            a1 = fmaf(bfhi(g), q, a1);
        }
    }
    a0 += __shfl_xor(a0, 32);
    a1 += __shfl_xor(a1, 32);
    bool fin = lane < 20;   // lower half only (values duplicated on lanes 32-51)
    float l0 = a0, l1 = a1;
    if (fin) {
        float2 b = *(const float2*)&b3[lane * 2];
        l0 += b.x;
        l1 += b.y;
    }
    float m = fin ? fmaxf(l0, l1) : -1e30f;
#pragma unroll
    for (int off = 32; off > 0; off >>= 1) m = fmaxf(m, __shfl_xor(m, off));
    float s = fin ? (expf(l0 - m) + expf(l1 - m)) : 0.0f;
#pragma unroll
    for (int off = 32; off > 0; off >>= 1) s += __shfl_xor(s, off);
    float lse = m + logf(s);
    if (fin) *(float2*)&out[(size_t)node * CLS + lane * 2] = make_float2(l0 - lse, l1 - lse);
}

// ---------------- batchnorm stats ----------------

__global__ void zero_stats(float* stats) {
    if (threadIdx.x < 256) stats[threadIdx.x] = 0.0f;
}

__global__ __launch_bounds__(128) void bn_stats(const float* __restrict__ a,
                                                float* __restrict__ stats, int n) {
    int f = threadIdx.x;
    float s = 0.0f, s2 = 0.0f;
    for (int i = blockIdx.x; i < n; i += gridDim.x) {
        float v = a[(size_t)i * 128 + f];
        s += v;
        s2 = fmaf(v, v, s2);
    }
    atomicAdd(&stats[f], s);
    atomicAdd(&stats[128 + f], s2);
}

__global__ void finalize_scsh(const float* __restrict__ stats, const float* __restrict__ g,
                              const float* __restrict__ be, float* __restrict__ scsh) {
    int f = threadIdx.x;   // 128 threads
    float mean = stats[f] * (1.0f / (float)NN);
    float var = stats[128 + f] * (1.0f / (float)NN) - mean * mean;
    float sc = g[f] * rsqrtf(var + EPSBN);
    scsh[f] = sc;
    scsh[128 + f] = be[f] - mean * sc;
}

// ---------------- launcher ----------------

extern "C" void kernel_launch(void* const* d_in, const int* in_sizes, int n_in,
                              void* d_out, int out_size, void* d_ws, size_t ws_size,
                              hipStream_t stream) {
    const float* x   = (const float*)d_in[0];
    const int*   ei  = (const int*)d_in[1];
    const float* W1  = (const float*)d_in[2];
    const float* b1  = (const float*)d_in[3];
    const float* g1  = (const float*)d_in[4];
    const float* be1 = (const float*)d_in[5];
    const float* W2  = (const float*)d_in[6];
    const float* b2  = (const float*)d_in[7];
    const float* g2  = (const float*)d_in[8];
    const float* be2 = (const float*)d_in[9];
    const float* W3  = (const float*)d_in[10];
    const float* b3  = (const float*)d_in[11];
    float* out = (float*)d_out;

    const int* src = ei;
    const int* dst = ei + EE;

    char* w = (char*)d_ws;
    size_t off = 0;
    auto alloc = [&](size_t bytes) {
        void* p = w + off;
        off += (bytes + 255) & ~(size_t)255;
        return p;
    };
    float* dinv      = (float*)alloc((size_t)NN * 4);
    int*   counts    = (int*)alloc((size_t)NN * 4);
    int*   row_ptr   = (int*)alloc((size_t)(NN + 1) * 4);
    int*   cursor    = (int*)alloc((size_t)NN * 4);
    int*   blocksums = (int*)alloc(256 * 4);
    int*   bcur      = (int*)alloc((size_t)NBUK * 16 * 4);
    int*   tmp       = (int*)alloc((size_t)EE * 4);
    int2*  csr       = (int2*)alloc((size_t)EE * 8);
    float* stats     = (float*)alloc(256 * 4);
    float* scsh      = (float*)alloc(256 * 4);
    unsigned* Wf1    = (unsigned*)alloc(8192 * 4);
    unsigned* Wf2    = (unsigned*)alloc(8192 * 4);
    unsigned* Wf3    = (unsigned*)alloc(3072 * 4);
    float* aF        = (float*)alloc((size_t)NN * 128 * 4);   // fp32 agg output
    unsigned* hB     = (unsigned*)alloc((size_t)NN * 64 * 4); // bf16 h (pairs)
    unsigned* h3     = (unsigned*)alloc((size_t)NN * 20 * 4); // bf16 h3 (pairs)

    const int NB_N = (NN + 255) / 256;
    const int NB_E = (EE + 255) / 256;
    const int NSB  = (NN + 1023) / 1024;
    const int NB_G = (NN + 63) / 64;

    // ---- graph preprocessing + weight prep ----
    init_counts<<<NB_N, 256, 0, stream>>>(counts, NN);
    edge_count<<<NB_E, 256, 0, stream>>>(dst, counts, EE);
    make_dinv<<<NB_N, 256, 0, stream>>>(counts, dinv, NN);
    scan1<<<NSB, 1024, 0, stream>>>(counts, blocksums, NN);
    scan2<<<1, 128, 0, stream>>>(blocksums, NSB);
    scan3<<<NB_N, 256, 0, stream>>>(counts, blocksums, row_ptr, cursor, NN);
    init_bcur<<<(NBUK + 255) / 256, 256, 0, stream>>>(row_ptr, bcur);
    fill_p1<<<NB_E, 256, 0, stream>>>(src, dst, bcur, tmp, EE);
    fill_p2<<<NBUK, 256, 0, stream>>>(tmp, row_ptr, dinv, cursor, csr);
    prep_w128<<<32, 256, 0, stream>>>(W1, Wf1);
    prep_w128<<<32, 256, 0, stream>>>(W2, Wf2);
    prep_w40<<<12, 256, 0, stream>>>(W3, Wf3);

    // ---- layer 1 ----
    gemm128_mfma<0><<<NB_G, 256, 0, stream>>>(x, Wf1, nullptr, nullptr, hB);
    agg128_bf16<<<NN / 4, 256, 0, stream>>>((const uint2*)hB, row_ptr, csr, dinv, b1, aF);
    zero_stats<<<1, 256, 0, stream>>>(stats);
    bn_stats<<<512, 128, 0, stream>>>(aF, stats, NN);
    finalize_scsh<<<1, 128, 0, stream>>>(stats, g1, be1, scsh);

    // ---- layer 2 (BN1 + residual + relu fused into A-fragment load) ----
    gemm128_mfma<1><<<NB_G, 256, 0, stream>>>(aF, Wf2, scsh, x, hB);
    agg128_bf16<<<NN / 4, 256, 0, stream>>>((const uint2*)hB, row_ptr, csr, dinv, b2, aF);
    zero_stats<<<1, 256, 0, stream>>>(stats);
    bn_stats<<<512, 128, 0, stream>>>(aF, stats, NN);
    finalize_scsh<<<1, 128, 0, stream>>>(stats, g2, be2, scsh);

    // ---- layer 3 (BN2 + relu fused into A-fragment load) ----
    gemm40_mfma<<<NB_G, 256, 0, stream>>>(aF, Wf3, scsh, h3);
    agg40_lsm<<<NN / 4, 256, 0, stream>>>(h3, row_ptr, csr, dinv, b3, out);
}

// Round 5
// 645.010 us; speedup vs baseline: 1.0113x; 1.0113x over previous
//
#include <hip/hip_runtime.h>
#include <hip/hip_bf16.h>

#define NN 100000
#define EE 1600000
#define HID 128
#define CLS 40
#define EPSBN 1e-5f
#define NBUK ((NN + 63) >> 6)   // 1563 buckets of 64 nodes

typedef float f32x4 __attribute__((ext_vector_type(4)));
typedef short s16x8 __attribute__((ext_vector_type(8)));
union U48 { uint4 u; s16x8 s; };

static __device__ __forceinline__ unsigned short f2bf(float f) {
    unsigned u = __float_as_uint(f);
    unsigned r = (u + 0x7fff + ((u >> 16) & 1)) >> 16;   // RNE
    return (unsigned short)r;
}
static __device__ __forceinline__ unsigned pack2(float a, float b) {
    return (unsigned)f2bf(a) | ((unsigned)f2bf(b) << 16);
}
static __device__ __forceinline__ float bflo(unsigned v) { return __uint_as_float(v << 16); }
static __device__ __forceinline__ float bfhi(unsigned v) { return __uint_as_float(v & 0xffff0000u); }

// ---------------- degree / CSR build ----------------

__global__ void init_counts(int* counts, float* stats1, float* stats2, int n) {
    int i = blockIdx.x * 256 + threadIdx.x;
    if (i < n) counts[i] = 0;
    if (blockIdx.x == 0) {
        stats1[threadIdx.x] = 0.0f;
        stats2[threadIdx.x] = 0.0f;
    }
}

__global__ void edge_count(const int* __restrict__ dst, int* counts, int e) {
    int i = blockIdx.x * 256 + threadIdx.x;
    if (i < e) atomicAdd(&counts[dst[i]], 1);
}

__global__ void make_dinv(const int* __restrict__ counts, float* dinv, int n) {
    int i = blockIdx.x * 256 + threadIdx.x;
    if (i < n) dinv[i] = rsqrtf((float)(counts[i] + 1));   // +1 self loop
}

__global__ __launch_bounds__(1024) void scan1(int* counts, int* blocksums, int n) {
    __shared__ int tmp[1024];
    int tid = threadIdx.x;
    int gid = blockIdx.x * 1024 + tid;
    int v = (gid < n) ? counts[gid] : 0;
    tmp[tid] = v;
    __syncthreads();
    for (int off = 1; off < 1024; off <<= 1) {
        int t = (tid >= off) ? tmp[tid - off] : 0;
        __syncthreads();
        tmp[tid] += t;
        __syncthreads();
    }
    if (gid < n) counts[gid] = tmp[tid];
    if (tid == 1023) blocksums[blockIdx.x] = tmp[1023];
}

__global__ void scan2(int* blocksums, int nb) {
    __shared__ int tmp[128];
    int tid = threadIdx.x;
    int v = (tid < nb) ? blocksums[tid] : 0;
    tmp[tid] = v;
    __syncthreads();
    for (int off = 1; off < 128; off <<= 1) {
        int t = (tid >= off) ? tmp[tid - off] : 0;
        __syncthreads();
        tmp[tid] += t;
        __syncthreads();
    }
    if (tid < nb) blocksums[tid] = (tid == 0) ? 0 : tmp[tid - 1];
}

__global__ void scan3(const int* __restrict__ incl, const int* __restrict__ blocksums,
                      int* row_ptr, int* cursor, int n) {
    int gid = blockIdx.x * 256 + threadIdx.x;
    if (gid >= n) return;
    int inc = incl[gid] + blocksums[gid >> 10];
    row_ptr[gid + 1] = inc;
    int start = (gid == 0) ? 0 : incl[gid - 1] + blocksums[(gid - 1) >> 10];
    cursor[gid] = start;
    if (gid == 0) row_ptr[0] = 0;
}

// bucket cursors: one per 64-node range, padded to 1 line (16 ints)
__global__ void init_bcur(const int* __restrict__ row_ptr, int* bcur) {
    int b = blockIdx.x * 256 + threadIdx.x;
    if (b < NBUK) bcur[b * 16] = row_ptr[b << 6];
}

// phase 1: scatter edge into its dst bucket region (frontier = 1563 hot lines)
__global__ void fill_p1(const int* __restrict__ src, const int* __restrict__ dst,
                        int* bcur, int* __restrict__ tmp, int e) {
    int i = blockIdx.x * 256 + threadIdx.x;
    if (i >= e) return;
    int s = src[i], d = dst[i];
    int p = atomicAdd(&bcur[(d >> 6) * 16], 1);
    tmp[p] = (s << 6) | (d & 63);          // s < 2^17, 23 bits total
}

// phase 2: one block per bucket; re-scatter within ~8KB L2-hot window
__global__ __launch_bounds__(256) void fill_p2(const int* __restrict__ tmp,
                                               const int* __restrict__ row_ptr,
                                               const float* __restrict__ dinv,
                                               int* cursor, int2* __restrict__ csr) {
    int b = blockIdx.x;
    int lo = row_ptr[b << 6];
    int hiN = (b + 1) << 6;
    int hi = row_ptr[hiN > NN ? NN : hiN];
    for (int idx = lo + threadIdx.x; idx < hi; idx += 256) {
        int v = tmp[idx];
        int s = ((unsigned)v) >> 6;
        int d = (b << 6) | (v & 63);
        int p = atomicAdd(&cursor[d], 1);
        csr[p] = make_int2(s, __float_as_int(dinv[s] * dinv[d]));
    }
}

// ---------------- W pre-pack into MFMA B-fragment layout ----------------

__global__ void prep_w128(const float* __restrict__ W, unsigned* __restrict__ Wf) {
    int t = blockIdx.x * 256 + threadIdx.x;   // < 8192
    int q = t & 3, lane = (t >> 2) & 63, f = t >> 8;
    int ks = f >> 3, ct = f & 7;
    int k = ks * 32 + ((lane >> 4) << 3) + q * 2;
    int col = ct * 16 + (lane & 15);
    Wf[t] = pack2(W[k * 128 + col], W[(k + 1) * 128 + col]);
}

__global__ void prep_w40(const float* __restrict__ W, unsigned* __restrict__ Wf) {
    int t = blockIdx.x * 256 + threadIdx.x;   // < 3072
    int q = t & 3, lane = (t >> 2) & 63, f = t >> 8;
    int ks = f / 3, ct = f - ks * 3;
    int k = ks * 32 + ((lane >> 4) << 3) + q * 2;
    int col = ct * 16 + (lane & 15);
    float v0 = (col < CLS) ? W[k * CLS + col] : 0.0f;
    float v1 = (col < CLS) ? W[(k + 1) * CLS + col] : 0.0f;
    Wf[t] = pack2(v0, v1);
}

// ---------------- MFMA GEMMs ----------------

template <int MODE>
__global__ __launch_bounds__(256) void gemm128_mfma(const float* __restrict__ X,
                                                    const unsigned* __restrict__ Wf,
                                                    const float* __restrict__ scsh,
                                                    const float* __restrict__ xres,
                                                    unsigned* __restrict__ Hb) {
    int t = threadIdx.x;
    int lane = t & 63, w = t >> 6;
    int wr = w >> 1, wc = w & 1;
    int row_base = blockIdx.x * 64 + wr * 32;

    s16x8 b[4][4];
    const uint4* Wv = (const uint4*)Wf;
#pragma unroll
    for (int ks = 0; ks < 4; ks++)
#pragma unroll
        for (int ct = 0; ct < 4; ct++) {
            int f = ks * 8 + wc * 4 + ct;
            U48 u; u.u = Wv[f * 64 + lane];
            b[ks][ct] = u.s;
        }

    f32x4 acc[2][4] = {};
    int lrow = lane & 15;
    int koff = (lane >> 4) << 3;

#pragma unroll
    for (int ks = 0; ks < 4; ks++) {
        int k0 = ks * 32 + koff;
        float sc[8], sh[8];
        if (MODE == 1) {
            float4 s0 = *(const float4*)&scsh[k0];
            float4 s1 = *(const float4*)&scsh[k0 + 4];
            float4 h0 = *(const float4*)&scsh[128 + k0];
            float4 h1 = *(const float4*)&scsh[128 + k0 + 4];
            sc[0]=s0.x; sc[1]=s0.y; sc[2]=s0.z; sc[3]=s0.w;
            sc[4]=s1.x; sc[5]=s1.y; sc[6]=s1.z; sc[7]=s1.w;
            sh[0]=h0.x; sh[1]=h0.y; sh[2]=h0.z; sh[3]=h0.w;
            sh[4]=h1.x; sh[5]=h1.y; sh[6]=h1.z; sh[7]=h1.w;
        }
#pragma unroll
        for (int rf = 0; rf < 2; rf++) {
            int row = row_base + rf * 16 + lrow;
            float v[8];
            if (row < NN) {
                float4 a0 = *(const float4*)&X[(size_t)row * 128 + k0];
                float4 a1 = *(const float4*)&X[(size_t)row * 128 + k0 + 4];
                v[0]=a0.x; v[1]=a0.y; v[2]=a0.z; v[3]=a0.w;
                v[4]=a1.x; v[5]=a1.y; v[6]=a1.z; v[7]=a1.w;
                if (MODE == 1) {
                    float4 r0 = *(const float4*)&xres[(size_t)row * 128 + k0];
                    float4 r1 = *(const float4*)&xres[(size_t)row * 128 + k0 + 4];
                    float rr[8] = {r0.x,r0.y,r0.z,r0.w,r1.x,r1.y,r1.z,r1.w};
#pragma unroll
                    for (int j = 0; j < 8; j++)
                        v[j] = fmaxf(fmaf(v[j], sc[j], sh[j]) + rr[j], 0.0f);
                }
            } else {
#pragma unroll
                for (int j = 0; j < 8; j++) v[j] = 0.0f;
            }
            U48 a;
            a.u = make_uint4(pack2(v[0], v[1]), pack2(v[2], v[3]),
                             pack2(v[4], v[5]), pack2(v[6], v[7]));
#pragma unroll
            for (int ct = 0; ct < 4; ct++)
                acc[rf][ct] = __builtin_amdgcn_mfma_f32_16x16x32_bf16(a.s, b[ks][ct], acc[rf][ct], 0, 0, 0);
        }
    }

    unsigned short* Hs = (unsigned short*)Hb;
#pragma unroll
    for (int rf = 0; rf < 2; rf++)
#pragma unroll
        for (int ct = 0; ct < 4; ct++) {
            int col = wc * 64 + ct * 16 + lrow;
            int rbase = row_base + rf * 16 + ((lane >> 4) << 2);
#pragma unroll
            for (int r = 0; r < 4; r++) {
                int row = rbase + r;
                if (row < NN) Hs[(size_t)row * 128 + col] = f2bf(acc[rf][ct][r]);
            }
        }
}

__global__ __launch_bounds__(256) void gemm40_mfma(const float* __restrict__ X,
                                                   const unsigned* __restrict__ Wf,
                                                   const float* __restrict__ scsh,
                                                   unsigned* __restrict__ H3) {
    int t = threadIdx.x;
    int lane = t & 63, w = t >> 6;
    int row_base = blockIdx.x * 64 + w * 16;

    s16x8 b[4][3];
    const uint4* Wv = (const uint4*)Wf;
#pragma unroll
    for (int ks = 0; ks < 4; ks++)
#pragma unroll
        for (int ct = 0; ct < 3; ct++) {
            U48 u; u.u = Wv[(ks * 3 + ct) * 64 + lane];
            b[ks][ct] = u.s;
        }

    f32x4 acc[3] = {};
    int lrow = lane & 15;
    int koff = (lane >> 4) << 3;

#pragma unroll
    for (int ks = 0; ks < 4; ks++) {
        int k0 = ks * 32 + koff;
        float4 s0 = *(const float4*)&scsh[k0];
        float4 s1 = *(const float4*)&scsh[k0 + 4];
        float4 h0 = *(const float4*)&scsh[128 + k0];
        float4 h1 = *(const float4*)&scsh[128 + k0 + 4];
        float sc[8] = {s0.x,s0.y,s0.z,s0.w,s1.x,s1.y,s1.z,s1.w};
        float sh[8] = {h0.x,h0.y,h0.z,h0.w,h1.x,h1.y,h1.z,h1.w};
        int row = row_base + lrow;
        float v[8];
        if (row < NN) {
            float4 a0 = *(const float4*)&X[(size_t)row * 128 + k0];
            float4 a1 = *(const float4*)&X[(size_t)row * 128 + k0 + 4];
            float av[8] = {a0.x,a0.y,a0.z,a0.w,a1.x,a1.y,a1.z,a1.w};
#pragma unroll
            for (int j = 0; j < 8; j++)
                v[j] = fmaxf(fmaf(av[j], sc[j], sh[j]), 0.0f);
        } else {
#pragma unroll
            for (int j = 0; j < 8; j++) v[j] = 0.0f;
        }
        U48 a;
        a.u = make_uint4(pack2(v[0], v[1]), pack2(v[2], v[3]),
                         pack2(v[4], v[5]), pack2(v[6], v[7]));
#pragma unroll
        for (int ct = 0; ct < 3; ct++)
            acc[ct] = __builtin_amdgcn_mfma_f32_16x16x32_bf16(a.s, b[ks][ct], acc[ct], 0, 0, 0);
    }

    unsigned short* Hs = (unsigned short*)H3;
#pragma unroll
    for (int ct = 0; ct < 3; ct++) {
        int col = ct * 16 + lrow;
        if (col >= CLS) continue;
        int rbase = row_base + ((lane >> 4) << 2);
#pragma unroll
        for (int r = 0; r < 4; r++) {
            int row = rbase + r;
            if (row < NN) Hs[(size_t)row * CLS + col] = f2bf(acc[ct][r]);
        }
    }
}

// ---------------- aggregation ----------------

// wave per node; lane = feature pair; one edge per gather, 8 in flight
__global__ __launch_bounds__(256) void agg128_bf16(const unsigned* __restrict__ h,
                                                   const int* __restrict__ row_ptr,
                                                   const int2* __restrict__ csr,
                                                   const float* __restrict__ dinv,
                                                   const float* __restrict__ bias,
                                                   float* __restrict__ out) {
    int wid = threadIdx.x >> 6;
    int lane = threadIdx.x & 63;
    int node = blockIdx.x * 4 + wid;
    float di = dinv[node];
    float c0 = di * di;
    unsigned v = h[(size_t)node * 64 + lane];
    float a0 = bflo(v) * c0;
    float a1 = bfhi(v) * c0;
    int beg = row_ptr[node], end = row_ptr[node + 1];
    int e = beg;
    for (; e + 8 <= end; e += 8) {
        int2 p0 = csr[e],     p1 = csr[e + 1], p2 = csr[e + 2], p3 = csr[e + 3];
        int2 p4 = csr[e + 4], p5 = csr[e + 5], p6 = csr[e + 6], p7 = csr[e + 7];
        unsigned g0 = h[(size_t)p0.x * 64 + lane];
        unsigned g1 = h[(size_t)p1.x * 64 + lane];
        unsigned g2 = h[(size_t)p2.x * 64 + lane];
        unsigned g3 = h[(size_t)p3.x * 64 + lane];
        unsigned g4 = h[(size_t)p4.x * 64 + lane];
        unsigned g5 = h[(size_t)p5.x * 64 + lane];
        unsigned g6 = h[(size_t)p6.x * 64 + lane];
        unsigned g7 = h[(size_t)p7.x * 64 + lane];
        float q0 = __int_as_float(p0.y), q1 = __int_as_float(p1.y);
        float q2 = __int_as_float(p2.y), q3 = __int_as_float(p3.y);
        float q4 = __int_as_float(p4.y), q5 = __int_as_float(p5.y);
        float q6 = __int_as_float(p6.y), q7 = __int_as_float(p7.y);
        a0 = fmaf(bflo(g0), q0, a0); a1 = fmaf(bfhi(g0), q0, a1);
        a0 = fmaf(bflo(g1), q1, a0); a1 = fmaf(bfhi(g1), q1, a1);
        a0 = fmaf(bflo(g2), q2, a0); a1 = fmaf(bfhi(g2), q2, a1);
        a0 = fmaf(bflo(g3), q3, a0); a1 = fmaf(bfhi(g3), q3, a1);
        a0 = fmaf(bflo(g4), q4, a0); a1 = fmaf(bfhi(g4), q4, a1);
        a0 = fmaf(bflo(g5), q5, a0); a1 = fmaf(bfhi(g5), q5, a1);
        a0 = fmaf(bflo(g6), q6, a0); a1 = fmaf(bfhi(g6), q6, a1);
        a0 = fmaf(bflo(g7), q7, a0); a1 = fmaf(bfhi(g7), q7, a1);
    }
    for (; e < end; ++e) {
        int2 p = csr[e];
        float q = __int_as_float(p.y);
        unsigned g = h[(size_t)p.x * 64 + lane];
        a0 = fmaf(bflo(g), q, a0);
        a1 = fmaf(bfhi(g), q, a1);
    }
    float2 b = *(const float2*)&bias[lane * 2];
    *(float2*)&out[(size_t)node * 128 + lane * 2] = make_float2(a0 + b.x, a1 + b.y);
}

// layer-3: 3-slot layout — lane = slot*20 + fp; one gather covers 3 edges (60 lanes)
__global__ __launch_bounds__(256) void agg40_lsm(const unsigned* __restrict__ h3,
                                                 const int* __restrict__ row_ptr,
                                                 const int2* __restrict__ csr,
                                                 const float* __restrict__ dinv,
                                                 const float* __restrict__ b3,
                                                 float* __restrict__ out) {
    int wid = threadIdx.x >> 6;
    int lane = threadIdx.x & 63;
    int slot = lane / 20;          // 0,1,2 (3 = idle lanes 60-63)
    int fp = lane - slot * 20;     // feature pair 0..19
    bool slot_ok = slot < 3;
    int node = blockIdx.x * 4 + wid;
    float di = dinv[node];
    float c0 = di * di;
    float a0 = 0.0f, a1 = 0.0f;
    if (slot == 0) {
        unsigned v = h3[(size_t)node * 20 + fp];
        a0 = bflo(v) * c0;
        a1 = bfhi(v) * c0;
    }
    int beg = row_ptr[node], end = row_ptr[node + 1];
    int e = beg;
    for (; e + 12 <= end; e += 12) {       // lanes60-63 (slot3) read e+3.. — in bounds, unused
        int2 p0 = csr[e + slot];
        int2 p1 = csr[e + 3 + slot];
        int2 p2 = csr[e + 6 + slot];
        int2 p3 = csr[e + 9 + slot];
        unsigned g0 = h3[(size_t)p0.x * 20 + fp];
        unsigned g1 = h3[(size_t)p1.x * 20 + fp];
        unsigned g2 = h3[(size_t)p2.x * 20 + fp];
        unsigned g3 = h3[(size_t)p3.x * 20 + fp];
        float q0 = __int_as_float(p0.y), q1 = __int_as_float(p1.y);
        float q2 = __int_as_float(p2.y), q3 = __int_as_float(p3.y);
        a0 = fmaf(bflo(g0), q0, a0); a1 = fmaf(bfhi(g0), q0, a1);
        a0 = fmaf(bflo(g1), q1, a0); a1 = fmaf(bfhi(g1), q1, a1);
        a0 = fmaf(bflo(g2), q2, a0); a1 = fmaf(bfhi(g2), q2, a1);
        a0 = fmaf(bflo(g3), q3, a0); a1 = fmaf(bfhi(g3), q3, a1);
    }
    for (; e < end; e += 3) {
        int idx = e + slot;
        bool act = slot_ok && (idx < end);
        int2 p = csr[act ? idx : (end - 1)];
        float q = act ? __int_as_float(p.y) : 0.0f;
        unsigned g = h3[(size_t)p.x * 20 + fp];
        a0 = fmaf(bflo(g), q, a0);
        a1 = fmaf(bfhi(g), q, a1);
    }
    // merge slots: lanes 0-19 pull slot1 (lane+20) and slot2 (lane+40)
    float s1a = __shfl(a0, lane + 20), s1b = __shfl(a1, lane + 20);
    float s2a = __shfl(a0, lane + 40), s2b = __shfl(a1, lane + 40);
    bool fin = lane < 20;
    float l0 = 0.0f, l1 = 0.0f;
    if (fin) {
        float2 b = *(const float2*)&b3[lane * 2];
        l0 = a0 + s1a + s2a + b.x;
        l1 = a1 + s1b + s2b + b.y;
    }
    float m = fin ? fmaxf(l0, l1) : -1e30f;
#pragma unroll
    for (int off = 32; off > 0; off >>= 1) m = fmaxf(m, __shfl_xor(m, off));
    float s = fin ? (expf(l0 - m) + expf(l1 - m)) : 0.0f;
#pragma unroll
    for (int off = 32; off > 0; off >>= 1) s += __shfl_xor(s, off);
    float lse = m + logf(s);
    if (fin) *(float2*)&out[(size_t)node * CLS + lane * 2] = make_float2(l0 - lse, l1 - lse);
}

// ---------------- batchnorm stats ----------------

__global__ __launch_bounds__(128) void bn_stats(const float* __restrict__ a,
                                                float* __restrict__ stats, int n) {
    int f = threadIdx.x;
    float s = 0.0f, s2 = 0.0f;
    for (int i = blockIdx.x; i < n; i += gridDim.x) {
        float v = a[(size_t)i * 128 + f];
        s += v;
        s2 = fmaf(v, v, s2);
    }
    atomicAdd(&stats[f], s);
    atomicAdd(&stats[128 + f], s2);
}

__global__ void finalize_scsh(const float* __restrict__ stats, const float* __restrict__ g,
                              const float* __restrict__ be, float* __restrict__ scsh) {
    int f = threadIdx.x;   // 128 threads
    float mean = stats[f] * (1.0f / (float)NN);
    float var = stats[128 + f] * (1.0f / (float)NN) - mean * mean;
    float sc = g[f] * rsqrtf(var + EPSBN);
    scsh[f] = sc;
    scsh[128 + f] = be[f] - mean * sc;
}

// ---------------- launcher ----------------

extern "C" void kernel_launch(void* const* d_in, const int* in_sizes, int n_in,
                              void* d_out, int out_size, void* d_ws, size_t ws_size,
                              hipStream_t stream) {
    const float* x   = (const float*)d_in[0];
    const int*   ei  = (const int*)d_in[1];
    const float* W1  = (const float*)d_in[2];
    const float* b1  = (const float*)d_in[3];
    const float* g1  = (const float*)d_in[4];
    const float* be1 = (const float*)d_in[5];
    const float* W2  = (const float*)d_in[6];
    const float* b2  = (const float*)d_in[7];
    const float* g2  = (const float*)d_in[8];
    const float* be2 = (const float*)d_in[9];
    const float* W3  = (const float*)d_in[10];
    const float* b3  = (const float*)d_in[11];
    float* out = (float*)d_out;

    const int* src = ei;
    const int* dst = ei + EE;

    char* w = (char*)d_ws;
    size_t off = 0;
    auto alloc = [&](size_t bytes) {
        void* p = w + off;
        off += (bytes + 255) & ~(size_t)255;
        return p;
    };
    float* dinv      = (float*)alloc((size_t)NN * 4);
    int*   counts    = (int*)alloc((size_t)NN * 4);
    int*   row_ptr   = (int*)alloc((size_t)(NN + 1) * 4);
    int*   cursor    = (int*)alloc((size_t)NN * 4);
    int*   blocksums = (int*)alloc(256 * 4);
    int*   bcur      = (int*)alloc((size_t)NBUK * 16 * 4);
    int*   tmp       = (int*)alloc((size_t)EE * 4);
    int2*  csr       = (int2*)alloc((size_t)EE * 8);
    float* stats1    = (float*)alloc(256 * 4);
    float* stats2    = (float*)alloc(256 * 4);
    float* scsh      = (float*)alloc(256 * 4);
    unsigned* Wf1    = (unsigned*)alloc(8192 * 4);
    unsigned* Wf2    = (unsigned*)alloc(8192 * 4);
    unsigned* Wf3    = (unsigned*)alloc(3072 * 4);
    float* aF        = (float*)alloc((size_t)NN * 128 * 4);   // fp32 agg output
    unsigned* hB     = (unsigned*)alloc((size_t)NN * 64 * 4); // bf16 h (pairs)
    unsigned* h3     = (unsigned*)alloc((size_t)NN * 20 * 4); // bf16 h3 (pairs)

    const int NB_N = (NN + 255) / 256;
    const int NB_E = (EE + 255) / 256;
    const int NSB  = (NN + 1023) / 1024;
    const int NB_G = (NN + 63) / 64;

    // ---- graph preprocessing + weight prep ----
    init_counts<<<NB_N, 256, 0, stream>>>(counts, stats1, stats2, NN);
    edge_count<<<NB_E, 256, 0, stream>>>(dst, counts, EE);
    make_dinv<<<NB_N, 256, 0, stream>>>(counts, dinv, NN);
    scan1<<<NSB, 1024, 0, stream>>>(counts, blocksums, NN);
    scan2<<<1, 128, 0, stream>>>(blocksums, NSB);
    scan3<<<NB_N, 256, 0, stream>>>(counts, blocksums, row_ptr, cursor, NN);
    init_bcur<<<(NBUK + 255) / 256, 256, 0, stream>>>(row_ptr, bcur);
    fill_p1<<<NB_E, 256, 0, stream>>>(src, dst, bcur, tmp, EE);
    fill_p2<<<NBUK, 256, 0, stream>>>(tmp, row_ptr, dinv, cursor, csr);
    prep_w128<<<32, 256, 0, stream>>>(W1, Wf1);
    prep_w128<<<32, 256, 0, stream>>>(W2, Wf2);
    prep_w40<<<12, 256, 0, stream>>>(W3, Wf3);

    // ---- layer 1 ----
    gemm128_mfma<0><<<NB_G, 256, 0, stream>>>(x, Wf1, nullptr, nullptr, hB);
    agg128_bf16<<<NN / 4, 256, 0, stream>>>(hB, row_ptr, csr, dinv, b1, aF);
    bn_stats<<<512, 128, 0, stream>>>(aF, stats1, NN);
    finalize_scsh<<<1, 128, 0, stream>>>(stats1, g1, be1, scsh);

    // ---- layer 2 (BN1 + residual + relu fused into A-fragment load) ----
    gemm128_mfma<1><<<NB_G, 256, 0, stream>>>(aF, Wf2, scsh, x, hB);
    agg128_bf16<<<NN / 4, 256, 0, stream>>>(hB, row_ptr, csr, dinv, b2, aF);
    bn_stats<<<512, 128, 0, stream>>>(aF, stats2, NN);
    finalize_scsh<<<1, 128, 0, stream>>>(stats2, g2, be2, scsh);

    // ---- layer 3 (BN2 + relu fused into A-fragment load) ----
    gemm40_mfma<<<NB_G, 256, 0, stream>>>(aF, Wf3, scsh, h3);
    agg40_lsm<<<NN / 4, 256, 0, stream>>>(h3, row_ptr, csr, dinv, b3, out);
}

// Round 6
// 470.299 us; speedup vs baseline: 1.3869x; 1.3715x over previous
//
#include <hip/hip_runtime.h>
#include <hip/hip_bf16.h>

#define NN 100000
#define EE 1600000
#define HID 128
#define CLS 40
#define EPSBN 1e-5f
#define NBUK ((NN + 255) >> 8)     // 391 buckets of 256 nodes
#define CAP 6144                   // slots per bucket region (mean 4092, 32-sigma headroom)
#define EPB 4096                   // edges per p1 block

typedef float f32x4 __attribute__((ext_vector_type(4)));
typedef short s16x8 __attribute__((ext_vector_type(8)));
union U48 { uint4 u; s16x8 s; };

static __device__ __forceinline__ unsigned short f2bf(float f) {
    unsigned u = __float_as_uint(f);
    unsigned r = (u + 0x7fff + ((u >> 16) & 1)) >> 16;   // RNE
    return (unsigned short)r;
}
static __device__ __forceinline__ unsigned pack2(float a, float b) {
    return (unsigned)f2bf(a) | ((unsigned)f2bf(b) << 16);
}
static __device__ __forceinline__ float bflo(unsigned v) { return __uint_as_float(v << 16); }
static __device__ __forceinline__ float bfhi(unsigned v) { return __uint_as_float(v & 0xffff0000u); }

// ---------------- CSR build (LDS-binned, block-private write runs) ----------------

__global__ void init_misc(int* gcur, float* stats1, float* stats2) {
    int j = blockIdx.x * 256 + threadIdx.x;
    if (j < NBUK) gcur[j] = j * CAP;
    if (blockIdx.x == 0) {
        stats1[threadIdx.x] = 0.0f;
        stats2[threadIdx.x] = 0.0f;
    }
}

// phase 1: per-block LDS histogram -> contiguous per-bucket run reservation -> ranked scatter
__global__ __launch_bounds__(256) void fill_p1_binned(const int* __restrict__ src,
                                                      const int* __restrict__ dst,
                                                      int* gcur, int* __restrict__ tmp) {
    __shared__ int cnt[NBUK];
    __shared__ int base[NBUK];
    int tid = threadIdx.x;
    for (int j = tid; j < NBUK; j += 256) cnt[j] = 0;
    __syncthreads();

    int es[16], ed[16];
    int i0 = blockIdx.x * EPB;
#pragma unroll
    for (int k = 0; k < 16; k++) {
        int i = i0 + k * 256 + tid;
        bool ok = i < EE;
        es[k] = ok ? src[i] : -1;
        ed[k] = ok ? dst[i] : 0;
        if (ok) atomicAdd(&cnt[ed[k] >> 8], 1);
    }
    __syncthreads();
    for (int j = tid; j < NBUK; j += 256) {
        int c = cnt[j];
        base[j] = c ? atomicAdd(&gcur[j], c) : 0;
        cnt[j] = 0;
    }
    __syncthreads();
#pragma unroll
    for (int k = 0; k < 16; k++) {
        if (es[k] >= 0) {
            int b = ed[k] >> 8;
            int r = atomicAdd(&cnt[b], 1);
            tmp[base[b] + r] = (es[k] << 8) | (ed[k] & 255);
        }
    }
}

// exclusive scan of bucket totals -> csr bucket bases
__global__ __launch_bounds__(512) void bucket_scan(const int* __restrict__ gcur,
                                                   int* __restrict__ gbase,
                                                   int* __restrict__ row_ptr) {
    __shared__ int sc[512];
    int tid = threadIdx.x;
    int v = (tid < NBUK) ? gcur[tid] - tid * CAP : 0;
    sc[tid] = v;
    __syncthreads();
    for (int off = 1; off < 512; off <<= 1) {
        int t = (tid >= off) ? sc[tid - off] : 0;
        __syncthreads();
        sc[tid] += t;
        __syncthreads();
    }
    if (tid < NBUK) gbase[tid] = sc[tid] - v;
    if (tid == NBUK - 1) {
        gbase[NBUK] = sc[tid];
        row_ptr[NN] = sc[tid];
    }
}

// phase 2a: per-bucket node histogram -> dinv + row_ptr
__global__ __launch_bounds__(256) void fill_p2a(const int* __restrict__ tmp,
                                                const int* __restrict__ gcur,
                                                const int* __restrict__ gbase,
                                                float* __restrict__ dinv,
                                                int* __restrict__ row_ptr) {
    __shared__ int cnt[256];
    __shared__ int sc[256];
    int b = blockIdx.x;
    int tid = threadIdx.x;
    int total = gcur[b] - b * CAP;
    cnt[tid] = 0;
    __syncthreads();
    int lo = b * CAP;
    for (int k = tid; k < total; k += 256) atomicAdd(&cnt[tmp[lo + k] & 255], 1);
    __syncthreads();
    int c = cnt[tid];
    sc[tid] = c;
    __syncthreads();
    for (int off = 1; off < 256; off <<= 1) {
        int t = (tid >= off) ? sc[tid - off] : 0;
        __syncthreads();
        sc[tid] += t;
        __syncthreads();
    }
    int node = (b << 8) + tid;
    if (node < NN) {
        dinv[node] = rsqrtf((float)(c + 1));   // +1 self loop
        row_ptr[node] = gbase[b] + sc[tid] - c;
    }
}

// phase 2b: ranked scatter into csr within block-private window, coef computed here
__global__ __launch_bounds__(256) void fill_p2b(const int* __restrict__ tmp,
                                                const int* __restrict__ gcur,
                                                const float* __restrict__ dinv,
                                                const int* __restrict__ row_ptr,
                                                int2* __restrict__ csr) {
    __shared__ int cur[256];
    __shared__ float dlv[256];
    int b = blockIdx.x;
    int tid = threadIdx.x;
    int total = gcur[b] - b * CAP;
    int node = (b << 8) + tid;
    cur[tid] = (node < NN) ? row_ptr[node] : 0;
    dlv[tid] = (node < NN) ? dinv[node] : 0.0f;
    __syncthreads();
    int lo = b * CAP;
    for (int k = tid; k < total; k += 256) {
        int v = tmp[lo + k];
        int dl = v & 255;
        int s = ((unsigned)v) >> 8;
        int p = atomicAdd(&cur[dl], 1);
        csr[p] = make_int2(s, __float_as_int(dinv[s] * dlv[dl]));
    }
}

// ---------------- W pre-pack into MFMA B-fragment layout ----------------

__global__ void prep_w128(const float* __restrict__ W, unsigned* __restrict__ Wf) {
    int t = blockIdx.x * 256 + threadIdx.x;   // < 8192
    int q = t & 3, lane = (t >> 2) & 63, f = t >> 8;
    int ks = f >> 3, ct = f & 7;
    int k = ks * 32 + ((lane >> 4) << 3) + q * 2;
    int col = ct * 16 + (lane & 15);
    Wf[t] = pack2(W[k * 128 + col], W[(k + 1) * 128 + col]);
}

__global__ void prep_w40(const float* __restrict__ W, unsigned* __restrict__ Wf) {
    int t = blockIdx.x * 256 + threadIdx.x;   // < 3072
    int q = t & 3, lane = (t >> 2) & 63, f = t >> 8;
    int ks = f / 3, ct = f - ks * 3;
    int k = ks * 32 + ((lane >> 4) << 3) + q * 2;
    int col = ct * 16 + (lane & 15);
    float v0 = (col < CLS) ? W[k * CLS + col] : 0.0f;
    float v1 = (col < CLS) ? W[(k + 1) * CLS + col] : 0.0f;
    Wf[t] = pack2(v0, v1);
}

// ---------------- MFMA GEMMs ----------------

template <int MODE>
__global__ __launch_bounds__(256) void gemm128_mfma(const float* __restrict__ X,
                                                    const unsigned* __restrict__ Wf,
                                                    const float* __restrict__ scsh,
                                                    const float* __restrict__ xres,
                                                    unsigned* __restrict__ Hb) {
    int t = threadIdx.x;
    int lane = t & 63, w = t >> 6;
    int wr = w >> 1, wc = w & 1;
    int row_base = blockIdx.x * 64 + wr * 32;

    s16x8 b[4][4];
    const uint4* Wv = (const uint4*)Wf;
#pragma unroll
    for (int ks = 0; ks < 4; ks++)
#pragma unroll
        for (int ct = 0; ct < 4; ct++) {
            int f = ks * 8 + wc * 4 + ct;
            U48 u; u.u = Wv[f * 64 + lane];
            b[ks][ct] = u.s;
        }

    f32x4 acc[2][4] = {};
    int lrow = lane & 15;
    int koff = (lane >> 4) << 3;

#pragma unroll
    for (int ks = 0; ks < 4; ks++) {
        int k0 = ks * 32 + koff;
        float sc[8], sh[8];
        if (MODE == 1) {
            float4 s0 = *(const float4*)&scsh[k0];
            float4 s1 = *(const float4*)&scsh[k0 + 4];
            float4 h0 = *(const float4*)&scsh[128 + k0];
            float4 h1 = *(const float4*)&scsh[128 + k0 + 4];
            sc[0]=s0.x; sc[1]=s0.y; sc[2]=s0.z; sc[3]=s0.w;
            sc[4]=s1.x; sc[5]=s1.y; sc[6]=s1.z; sc[7]=s1.w;
            sh[0]=h0.x; sh[1]=h0.y; sh[2]=h0.z; sh[3]=h0.w;
            sh[4]=h1.x; sh[5]=h1.y; sh[6]=h1.z; sh[7]=h1.w;
        }
#pragma unroll
        for (int rf = 0; rf < 2; rf++) {
            int row = row_base + rf * 16 + lrow;
            float v[8];
            if (row < NN) {
                float4 a0 = *(const float4*)&X[(size_t)row * 128 + k0];
                float4 a1 = *(const float4*)&X[(size_t)row * 128 + k0 + 4];
                v[0]=a0.x; v[1]=a0.y; v[2]=a0.z; v[3]=a0.w;
                v[4]=a1.x; v[5]=a1.y; v[6]=a1.z; v[7]=a1.w;
                if (MODE == 1) {
                    float4 r0 = *(const float4*)&xres[(size_t)row * 128 + k0];
                    float4 r1 = *(const float4*)&xres[(size_t)row * 128 + k0 + 4];
                    float rr[8] = {r0.x,r0.y,r0.z,r0.w,r1.x,r1.y,r1.z,r1.w};
#pragma unroll
                    for (int j = 0; j < 8; j++)
                        v[j] = fmaxf(fmaf(v[j], sc[j], sh[j]) + rr[j], 0.0f);
                }
            } else {
#pragma unroll
                for (int j = 0; j < 8; j++) v[j] = 0.0f;
            }
            U48 a;
            a.u = make_uint4(pack2(v[0], v[1]), pack2(v[2], v[3]),
                             pack2(v[4], v[5]), pack2(v[6], v[7]));
#pragma unroll
            for (int ct = 0; ct < 4; ct++)
                acc[rf][ct] = __builtin_amdgcn_mfma_f32_16x16x32_bf16(a.s, b[ks][ct], acc[rf][ct], 0, 0, 0);
        }
    }

    unsigned short* Hs = (unsigned short*)Hb;
#pragma unroll
    for (int rf = 0; rf < 2; rf++)
#pragma unroll
        for (int ct = 0; ct < 4; ct++) {
            int col = wc * 64 + ct * 16 + lrow;
            int rbase = row_base + rf * 16 + ((lane >> 4) << 2);
#pragma unroll
            for (int r = 0; r < 4; r++) {
                int row = rbase + r;
                if (row < NN) Hs[(size_t)row * 128 + col] = f2bf(acc[rf][ct][r]);
            }
        }
}

__global__ __launch_bounds__(256) void gemm40_mfma(const float* __restrict__ X,
                                                   const unsigned* __restrict__ Wf,
                                                   const float* __restrict__ scsh,
                                                   unsigned* __restrict__ H3) {
    int t = threadIdx.x;
    int lane = t & 63, w = t >> 6;
    int row_base = blockIdx.x * 64 + w * 16;

    s16x8 b[4][3];
    const uint4* Wv = (const uint4*)Wf;
#pragma unroll
    for (int ks = 0; ks < 4; ks++)
#pragma unroll
        for (int ct = 0; ct < 3; ct++) {
            U48 u; u.u = Wv[(ks * 3 + ct) * 64 + lane];
            b[ks][ct] = u.s;
        }

    f32x4 acc[3] = {};
    int lrow = lane & 15;
    int koff = (lane >> 4) << 3;

#pragma unroll
    for (int ks = 0; ks < 4; ks++) {
        int k0 = ks * 32 + koff;
        float4 s0 = *(const float4*)&scsh[k0];
        float4 s1 = *(const float4*)&scsh[k0 + 4];
        float4 h0 = *(const float4*)&scsh[128 + k0];
        float4 h1 = *(const float4*)&scsh[128 + k0 + 4];
        float sc[8] = {s0.x,s0.y,s0.z,s0.w,s1.x,s1.y,s1.z,s1.w};
        float sh[8] = {h0.x,h0.y,h0.z,h0.w,h1.x,h1.y,h1.z,h1.w};
        int row = row_base + lrow;
        float v[8];
        if (row < NN) {
            float4 a0 = *(const float4*)&X[(size_t)row * 128 + k0];
            float4 a1 = *(const float4*)&X[(size_t)row * 128 + k0 + 4];
            float av[8] = {a0.x,a0.y,a0.z,a0.w,a1.x,a1.y,a1.z,a1.w};
#pragma unroll
            for (int j = 0; j < 8; j++)
                v[j] = fmaxf(fmaf(av[j], sc[j], sh[j]), 0.0f);
        } else {
#pragma unroll
            for (int j = 0; j < 8; j++) v[j] = 0.0f;
        }
        U48 a;
        a.u = make_uint4(pack2(v[0], v[1]), pack2(v[2], v[3]),
                         pack2(v[4], v[5]), pack2(v[6], v[7]));
#pragma unroll
        for (int ct = 0; ct < 3; ct++)
            acc[ct] = __builtin_amdgcn_mfma_f32_16x16x32_bf16(a.s, b[ks][ct], acc[ct], 0, 0, 0);
    }

    unsigned short* Hs = (unsigned short*)H3;
#pragma unroll
    for (int ct = 0; ct < 3; ct++) {
        int col = ct * 16 + lrow;
        if (col >= CLS) continue;
        int rbase = row_base + ((lane >> 4) << 2);
#pragma unroll
        for (int r = 0; r < 4; r++) {
            int row = rbase + r;
            if (row < NN) Hs[(size_t)row * CLS + col] = f2bf(acc[ct][r]);
        }
    }
}

// ---------------- aggregation ----------------

// wave per node; lane = feature pair; one edge per gather, 8 in flight
__global__ __launch_bounds__(256) void agg128_bf16(const unsigned* __restrict__ h,
                                                   const int* __restrict__ row_ptr,
                                                   const int2* __restrict__ csr,
                                                   const float* __restrict__ dinv,
                                                   const float* __restrict__ bias,
                                                   float* __restrict__ out) {
    int wid = threadIdx.x >> 6;
    int lane = threadIdx.x & 63;
    int node = blockIdx.x * 4 + wid;
    float di = dinv[node];
    float c0 = di * di;
    unsigned v = h[(size_t)node * 64 + lane];
    float a0 = bflo(v) * c0;
    float a1 = bfhi(v) * c0;
    int beg = row_ptr[node], end = row_ptr[node + 1];
    int e = beg;
    for (; e + 8 <= end; e += 8) {
        int2 p0 = csr[e],     p1 = csr[e + 1], p2 = csr[e + 2], p3 = csr[e + 3];
        int2 p4 = csr[e + 4], p5 = csr[e + 5], p6 = csr[e + 6], p7 = csr[e + 7];
        unsigned g0 = h[(size_t)p0.x * 64 + lane];
        unsigned g1 = h[(size_t)p1.x * 64 + lane];
        unsigned g2 = h[(size_t)p2.x * 64 + lane];
        unsigned g3 = h[(size_t)p3.x * 64 + lane];
        unsigned g4 = h[(size_t)p4.x * 64 + lane];
        unsigned g5 = h[(size_t)p5.x * 64 + lane];
        unsigned g6 = h[(size_t)p6.x * 64 + lane];
        unsigned g7 = h[(size_t)p7.x * 64 + lane];
        float q0 = __int_as_float(p0.y), q1 = __int_as_float(p1.y);
        float q2 = __int_as_float(p2.y), q3 = __int_as_float(p3.y);
        float q4 = __int_as_float(p4.y), q5 = __int_as_float(p5.y);
        float q6 = __int_as_float(p6.y), q7 = __int_as_float(p7.y);
        a0 = fmaf(bflo(g0), q0, a0); a1 = fmaf(bfhi(g0), q0, a1);
        a0 = fmaf(bflo(g1), q1, a0); a1 = fmaf(bfhi(g1), q1, a1);
        a0 = fmaf(bflo(g2), q2, a0); a1 = fmaf(bfhi(g2), q2, a1);
        a0 = fmaf(bflo(g3), q3, a0); a1 = fmaf(bfhi(g3), q3, a1);
        a0 = fmaf(bflo(g4), q4, a0); a1 = fmaf(bfhi(g4), q4, a1);
        a0 = fmaf(bflo(g5), q5, a0); a1 = fmaf(bfhi(g5), q5, a1);
        a0 = fmaf(bflo(g6), q6, a0); a1 = fmaf(bfhi(g6), q6, a1);
        a0 = fmaf(bflo(g7), q7, a0); a1 = fmaf(bfhi(g7), q7, a1);
    }
    for (; e < end; ++e) {
        int2 p = csr[e];
        float q = __int_as_float(p.y);
        unsigned g = h[(size_t)p.x * 64 + lane];
        a0 = fmaf(bflo(g), q, a0);
        a1 = fmaf(bfhi(g), q, a1);
    }
    float2 b = *(const float2*)&bias[lane * 2];
    *(float2*)&out[(size_t)node * 128 + lane * 2] = make_float2(a0 + b.x, a1 + b.y);
}

// layer-3: 3-slot layout — lane = slot*20 + fp; one gather covers 3 edges (60 lanes)
__global__ __launch_bounds__(256) void agg40_lsm(const unsigned* __restrict__ h3,
                                                 const int* __restrict__ row_ptr,
                                                 const int2* __restrict__ csr,
                                                 const float* __restrict__ dinv,
                                                 const float* __restrict__ b3,
                                                 float* __restrict__ out) {
    int wid = threadIdx.x >> 6;
    int lane = threadIdx.x & 63;
    int slot = lane / 20;          // 0,1,2 (3 = idle lanes 60-63)
    int fp = lane - slot * 20;     // feature pair 0..19
    bool slot_ok = slot < 3;
    int node = blockIdx.x * 4 + wid;
    float di = dinv[node];
    float c0 = di * di;
    float a0 = 0.0f, a1 = 0.0f;
    if (slot == 0) {
        unsigned v = h3[(size_t)node * 20 + fp];
        a0 = bflo(v) * c0;
        a1 = bfhi(v) * c0;
    }
    int beg = row_ptr[node], end = row_ptr[node + 1];
    int e = beg;
    for (; e + 12 <= end; e += 12) {
        int2 p0 = csr[e + slot];
        int2 p1 = csr[e + 3 + slot];
        int2 p2 = csr[e + 6 + slot];
        int2 p3 = csr[e + 9 + slot];
        unsigned g0 = h3[(size_t)p0.x * 20 + fp];
        unsigned g1 = h3[(size_t)p1.x * 20 + fp];
        unsigned g2 = h3[(size_t)p2.x * 20 + fp];
        unsigned g3 = h3[(size_t)p3.x * 20 + fp];
        float q0 = __int_as_float(p0.y), q1 = __int_as_float(p1.y);
        float q2 = __int_as_float(p2.y), q3 = __int_as_float(p3.y);
        a0 = fmaf(bflo(g0), q0, a0); a1 = fmaf(bfhi(g0), q0, a1);
        a0 = fmaf(bflo(g1), q1, a0); a1 = fmaf(bfhi(g1), q1, a1);
        a0 = fmaf(bflo(g2), q2, a0); a1 = fmaf(bfhi(g2), q2, a1);
        a0 = fmaf(bflo(g3), q3, a0); a1 = fmaf(bfhi(g3), q3, a1);
    }
    for (; e < end; e += 3) {
        int idx = e + slot;
        bool act = slot_ok && (idx < end);
        int2 p = csr[act ? idx : (end - 1)];
        float q = act ? __int_as_float(p.y) : 0.0f;
        unsigned g = h3[(size_t)p.x * 20 + fp];
        a0 = fmaf(bflo(g), q, a0);
        a1 = fmaf(bfhi(g), q, a1);
    }
    // merge slots: lanes 0-19 pull slot1 (lane+20) and slot2 (lane+40)
    float s1a = __shfl(a0, lane + 20), s1b = __shfl(a1, lane + 20);
    float s2a = __shfl(a0, lane + 40), s2b = __shfl(a1, lane + 40);
    bool fin = lane < 20;
    float l0 = 0.0f, l1 = 0.0f;
    if (fin) {
        float2 b = *(const float2*)&b3[lane * 2];
        l0 = a0 + s1a + s2a + b.x;
        l1 = a1 + s1b + s2b + b.y;
    }
    float m = fin ? fmaxf(l0, l1) : -1e30f;
#pragma unroll
    for (int off = 32; off > 0; off >>= 1) m = fmaxf(m, __shfl_xor(m, off));
    float s = fin ? (expf(l0 - m) + expf(l1 - m)) : 0.0f;
#pragma unroll
    for (int off = 32; off > 0; off >>= 1) s += __shfl_xor(s, off);
    float lse = m + logf(s);
    if (fin) *(float2*)&out[(size_t)node * CLS + lane * 2] = make_float2(l0 - lse, l1 - lse);
}

// ---------------- batchnorm stats ----------------

__global__ __launch_bounds__(128) void bn_stats(const float* __restrict__ a,
                                                float* __restrict__ stats, int n) {
    int f = threadIdx.x;
    float s = 0.0f, s2 = 0.0f;
    for (int i = blockIdx.x; i < n; i += gridDim.x) {
        float v = a[(size_t)i * 128 + f];
        s += v;
        s2 = fmaf(v, v, s2);
    }
    atomicAdd(&stats[f], s);
    atomicAdd(&stats[128 + f], s2);
}

__global__ void finalize_scsh(const float* __restrict__ stats, const float* __restrict__ g,
                              const float* __restrict__ be, float* __restrict__ scsh) {
    int f = threadIdx.x;   // 128 threads
    float mean = stats[f] * (1.0f / (float)NN);
    float var = stats[128 + f] * (1.0f / (float)NN) - mean * mean;
    float sc = g[f] * rsqrtf(var + EPSBN);
    scsh[f] = sc;
    scsh[128 + f] = be[f] - mean * sc;
}

// ---------------- launcher ----------------

extern "C" void kernel_launch(void* const* d_in, const int* in_sizes, int n_in,
                              void* d_out, int out_size, void* d_ws, size_t ws_size,
                              hipStream_t stream) {
    const float* x   = (const float*)d_in[0];
    const int*   ei  = (const int*)d_in[1];
    const float* W1  = (const float*)d_in[2];
    const float* b1  = (const float*)d_in[3];
    const float* g1  = (const float*)d_in[4];
    const float* be1 = (const float*)d_in[5];
    const float* W2  = (const float*)d_in[6];
    const float* b2  = (const float*)d_in[7];
    const float* g2  = (const float*)d_in[8];
    const float* be2 = (const float*)d_in[9];
    const float* W3  = (const float*)d_in[10];
    const float* b3  = (const float*)d_in[11];
    float* out = (float*)d_out;

    const int* src = ei;
    const int* dst = ei + EE;

    char* w = (char*)d_ws;
    size_t off = 0;
    auto alloc = [&](size_t bytes) {
        void* p = w + off;
        off += (bytes + 255) & ~(size_t)255;
        return p;
    };
    float* dinv      = (float*)alloc((size_t)NN * 4);
    int*   row_ptr   = (int*)alloc((size_t)(NN + 1) * 4);
    int*   gcur      = (int*)alloc((size_t)NBUK * 4);
    int*   gbase     = (int*)alloc((size_t)(NBUK + 1) * 4);
    int*   tmp       = (int*)alloc((size_t)NBUK * CAP * 4);   // 9.6 MB
    int2*  csr       = (int2*)alloc((size_t)EE * 8);
    float* stats1    = (float*)alloc(256 * 4);
    float* stats2    = (float*)alloc(256 * 4);
    float* scsh      = (float*)alloc(256 * 4);
    unsigned* Wf1    = (unsigned*)alloc(8192 * 4);
    unsigned* Wf2    = (unsigned*)alloc(8192 * 4);
    unsigned* Wf3    = (unsigned*)alloc(3072 * 4);
    float* aF        = (float*)alloc((size_t)NN * 128 * 4);   // fp32 agg output
    unsigned* hB     = (unsigned*)alloc((size_t)NN * 64 * 4); // bf16 h (pairs)
    unsigned* h3     = (unsigned*)alloc((size_t)NN * 20 * 4); // bf16 h3 (pairs)

    const int NB_P1 = (EE + EPB - 1) / EPB;   // 391
    const int NB_G  = (NN + 63) / 64;

    // ---- CSR build + weight prep ----
    init_misc<<<2, 256, 0, stream>>>(gcur, stats1, stats2);
    fill_p1_binned<<<NB_P1, 256, 0, stream>>>(src, dst, gcur, tmp);
    bucket_scan<<<1, 512, 0, stream>>>(gcur, gbase, row_ptr);
    fill_p2a<<<NBUK, 256, 0, stream>>>(tmp, gcur, gbase, dinv, row_ptr);
    fill_p2b<<<NBUK, 256, 0, stream>>>(tmp, gcur, dinv, row_ptr, csr);
    prep_w128<<<32, 256, 0, stream>>>(W1, Wf1);
    prep_w128<<<32, 256, 0, stream>>>(W2, Wf2);
    prep_w40<<<12, 256, 0, stream>>>(W3, Wf3);

    // ---- layer 1 ----
    gemm128_mfma<0><<<NB_G, 256, 0, stream>>>(x, Wf1, nullptr, nullptr, hB);
    agg128_bf16<<<NN / 4, 256, 0, stream>>>(hB, row_ptr, csr, dinv, b1, aF);
    bn_stats<<<512, 128, 0, stream>>>(aF, stats1, NN);
    finalize_scsh<<<1, 128, 0, stream>>>(stats1, g1, be1, scsh);

    // ---- layer 2 (BN1 + residual + relu fused into A-fragment load) ----
    gemm128_mfma<1><<<NB_G, 256, 0, stream>>>(aF, Wf2, scsh, x, hB);
    agg128_bf16<<<NN / 4, 256, 0, stream>>>(hB, row_ptr, csr, dinv, b2, aF);
    bn_stats<<<512, 128, 0, stream>>>(aF, stats2, NN);
    finalize_scsh<<<1, 128, 0, stream>>>(stats2, g2, be2, scsh);

    // ---- layer 3 (BN2 + relu fused into A-fragment load) ----
    gemm40_mfma<<<NB_G, 256, 0, stream>>>(aF, Wf3, scsh, h3);
    agg40_lsm<<<NN / 4, 256, 0, stream>>>(h3, row_ptr, csr, dinv, b3, out);
}

// Round 7
// 444.126 us; speedup vs baseline: 1.4687x; 1.0589x over previous
//
#include <hip/hip_runtime.h>
#include <hip/hip_bf16.h>

#define NN 100000
#define EE 1600000
#define HID 128
#define CLS 40
#define EPSBN 1e-5f
#define NBUK ((NN + 255) >> 8)     // 391 buckets of 256 nodes
#define CAP 6144                   // slots per bucket region (mean 4092, 32-sigma headroom)
#define EPB 4096                   // edges per p1 block

typedef float f32x4 __attribute__((ext_vector_type(4)));
typedef short s16x8 __attribute__((ext_vector_type(8)));
union U48 { uint4 u; s16x8 s; };

static __device__ __forceinline__ unsigned short f2bf(float f) {
    unsigned u = __float_as_uint(f);
    unsigned r = (u + 0x7fff + ((u >> 16) & 1)) >> 16;   // RNE
    return (unsigned short)r;
}
static __device__ __forceinline__ unsigned pack2(float a, float b) {
    return (unsigned)f2bf(a) | ((unsigned)f2bf(b) << 16);
}
static __device__ __forceinline__ float bflo(unsigned v) { return __uint_as_float(v << 16); }
static __device__ __forceinline__ float bfhi(unsigned v) { return __uint_as_float(v & 0xffff0000u); }

// ---------------- CSR build (LDS-binned, block-private write runs) ----------------

__global__ void init_misc(int* gcur, float* stats1, float* stats2) {
    int j = blockIdx.x * 256 + threadIdx.x;
    if (j < NBUK) gcur[j] = j * CAP;
    if (blockIdx.x == 0) {
        stats1[threadIdx.x] = 0.0f;
        stats2[threadIdx.x] = 0.0f;
    }
}

__global__ __launch_bounds__(256) void fill_p1_binned(const int* __restrict__ src,
                                                      const int* __restrict__ dst,
                                                      int* gcur, int* __restrict__ tmp) {
    __shared__ int cnt[NBUK];
    __shared__ int base[NBUK];
    int tid = threadIdx.x;
    for (int j = tid; j < NBUK; j += 256) cnt[j] = 0;
    __syncthreads();

    int es[16], ed[16];
    int i0 = blockIdx.x * EPB;
#pragma unroll
    for (int k = 0; k < 16; k++) {
        int i = i0 + k * 256 + tid;
        bool ok = i < EE;
        es[k] = ok ? src[i] : -1;
        ed[k] = ok ? dst[i] : 0;
        if (ok) atomicAdd(&cnt[ed[k] >> 8], 1);
    }
    __syncthreads();
    for (int j = tid; j < NBUK; j += 256) {
        int c = cnt[j];
        base[j] = c ? atomicAdd(&gcur[j], c) : 0;
        cnt[j] = 0;
    }
    __syncthreads();
#pragma unroll
    for (int k = 0; k < 16; k++) {
        if (es[k] >= 0) {
            int b = ed[k] >> 8;
            int r = atomicAdd(&cnt[b], 1);
            tmp[base[b] + r] = (es[k] << 8) | (ed[k] & 255);
        }
    }
}

__global__ __launch_bounds__(512) void bucket_scan(const int* __restrict__ gcur,
                                                   int* __restrict__ gbase,
                                                   int* __restrict__ row_ptr) {
    __shared__ int sc[512];
    int tid = threadIdx.x;
    int v = (tid < NBUK) ? gcur[tid] - tid * CAP : 0;
    sc[tid] = v;
    __syncthreads();
    for (int off = 1; off < 512; off <<= 1) {
        int t = (tid >= off) ? sc[tid - off] : 0;
        __syncthreads();
        sc[tid] += t;
        __syncthreads();
    }
    if (tid < NBUK) gbase[tid] = sc[tid] - v;
    if (tid == NBUK - 1) {
        gbase[NBUK] = sc[tid];
        row_ptr[NN] = sc[tid];
    }
}

__global__ __launch_bounds__(256) void fill_p2a(const int* __restrict__ tmp,
                                                const int* __restrict__ gcur,
                                                const int* __restrict__ gbase,
                                                float* __restrict__ dinv,
                                                int* __restrict__ row_ptr) {
    __shared__ int cnt[256];
    __shared__ int sc[256];
    int b = blockIdx.x;
    int tid = threadIdx.x;
    int total = gcur[b] - b * CAP;
    cnt[tid] = 0;
    __syncthreads();
    int lo = b * CAP;
    for (int k = tid; k < total; k += 256) atomicAdd(&cnt[tmp[lo + k] & 255], 1);
    __syncthreads();
    int c = cnt[tid];
    sc[tid] = c;
    __syncthreads();
    for (int off = 1; off < 256; off <<= 1) {
        int t = (tid >= off) ? sc[tid - off] : 0;
        __syncthreads();
        sc[tid] += t;
        __syncthreads();
    }
    int node = (b << 8) + tid;
    if (node < NN) {
        dinv[node] = rsqrtf((float)(c + 1));   // +1 self loop
        row_ptr[node] = gbase[b] + sc[tid] - c;
    }
}

__global__ __launch_bounds__(256) void fill_p2b(const int* __restrict__ tmp,
                                                const int* __restrict__ gcur,
                                                const float* __restrict__ dinv,
                                                const int* __restrict__ row_ptr,
                                                int2* __restrict__ csr) {
    __shared__ int cur[256];
    __shared__ float dlv[256];
    int b = blockIdx.x;
    int tid = threadIdx.x;
    int total = gcur[b] - b * CAP;
    int node = (b << 8) + tid;
    cur[tid] = (node < NN) ? row_ptr[node] : 0;
    dlv[tid] = (node < NN) ? dinv[node] : 0.0f;
    __syncthreads();
    int lo = b * CAP;
    for (int k = tid; k < total; k += 256) {
        int v = tmp[lo + k];
        int dl = v & 255;
        int s = ((unsigned)v) >> 8;
        int p = atomicAdd(&cur[dl], 1);
        csr[p] = make_int2(s, __float_as_int(dinv[s] * dlv[dl]));
    }
}

// ---------------- W pre-pack into MFMA B-fragment layout ----------------

__global__ void prep_w128(const float* __restrict__ W, unsigned* __restrict__ Wf) {
    int t = blockIdx.x * 256 + threadIdx.x;   // < 8192
    int q = t & 3, lane = (t >> 2) & 63, f = t >> 8;
    int ks = f >> 3, ct = f & 7;
    int k = ks * 32 + ((lane >> 4) << 3) + q * 2;
    int col = ct * 16 + (lane & 15);
    Wf[t] = pack2(W[k * 128 + col], W[(k + 1) * 128 + col]);
}

__global__ void prep_w40(const float* __restrict__ W, unsigned* __restrict__ Wf) {
    int t = blockIdx.x * 256 + threadIdx.x;   // < 3072
    int q = t & 3, lane = (t >> 2) & 63, f = t >> 8;
    int ks = f / 3, ct = f - ks * 3;
    int k = ks * 32 + ((lane >> 4) << 3) + q * 2;
    int col = ct * 16 + (lane & 15);
    float v0 = (col < CLS) ? W[k * CLS + col] : 0.0f;
    float v1 = (col < CLS) ? W[(k + 1) * CLS + col] : 0.0f;
    Wf[t] = pack2(v0, v1);
}

// ---------------- MFMA GEMMs ----------------

// MODE 0: A = Xf (fp32). MODE 1: A = relu(bn(Xb bf16) + xres fp32). Out bf16 H [N][128].
template <int MODE>
__global__ __launch_bounds__(256) void gemm128_mfma(const float* __restrict__ Xf,
                                                    const unsigned* __restrict__ Xb,
                                                    const unsigned* __restrict__ Wf,
                                                    const float* __restrict__ scsh,
                                                    const float* __restrict__ xres,
                                                    unsigned* __restrict__ Hb) {
    int t = threadIdx.x;
    int lane = t & 63, w = t >> 6;
    int wr = w >> 1, wc = w & 1;
    int row_base = blockIdx.x * 64 + wr * 32;

    s16x8 b[4][4];
    const uint4* Wv = (const uint4*)Wf;
#pragma unroll
    for (int ks = 0; ks < 4; ks++)
#pragma unroll
        for (int ct = 0; ct < 4; ct++) {
            int f = ks * 8 + wc * 4 + ct;
            U48 u; u.u = Wv[f * 64 + lane];
            b[ks][ct] = u.s;
        }

    f32x4 acc[2][4] = {};
    int lrow = lane & 15;
    int koff = (lane >> 4) << 3;

#pragma unroll
    for (int ks = 0; ks < 4; ks++) {
        int k0 = ks * 32 + koff;
        float sc[8], sh[8];
        if (MODE == 1) {
            float4 s0 = *(const float4*)&scsh[k0];
            float4 s1 = *(const float4*)&scsh[k0 + 4];
            float4 h0 = *(const float4*)&scsh[128 + k0];
            float4 h1 = *(const float4*)&scsh[128 + k0 + 4];
            sc[0]=s0.x; sc[1]=s0.y; sc[2]=s0.z; sc[3]=s0.w;
            sc[4]=s1.x; sc[5]=s1.y; sc[6]=s1.z; sc[7]=s1.w;
            sh[0]=h0.x; sh[1]=h0.y; sh[2]=h0.z; sh[3]=h0.w;
            sh[4]=h1.x; sh[5]=h1.y; sh[6]=h1.z; sh[7]=h1.w;
        }
#pragma unroll
        for (int rf = 0; rf < 2; rf++) {
            int row = row_base + rf * 16 + lrow;
            float v[8];
            if (row < NN) {
                if (MODE == 0) {
                    float4 a0 = *(const float4*)&Xf[(size_t)row * 128 + k0];
                    float4 a1 = *(const float4*)&Xf[(size_t)row * 128 + k0 + 4];
                    v[0]=a0.x; v[1]=a0.y; v[2]=a0.z; v[3]=a0.w;
                    v[4]=a1.x; v[5]=a1.y; v[6]=a1.z; v[7]=a1.w;
                } else {
                    uint4 u = *(const uint4*)&Xb[(size_t)row * 64 + k0 / 2];
                    v[0]=bflo(u.x); v[1]=bfhi(u.x); v[2]=bflo(u.y); v[3]=bfhi(u.y);
                    v[4]=bflo(u.z); v[5]=bfhi(u.z); v[6]=bflo(u.w); v[7]=bfhi(u.w);
                    float4 r0 = *(const float4*)&xres[(size_t)row * 128 + k0];
                    float4 r1 = *(const float4*)&xres[(size_t)row * 128 + k0 + 4];
                    float rr[8] = {r0.x,r0.y,r0.z,r0.w,r1.x,r1.y,r1.z,r1.w};
#pragma unroll
                    for (int j = 0; j < 8; j++)
                        v[j] = fmaxf(fmaf(v[j], sc[j], sh[j]) + rr[j], 0.0f);
                }
            } else {
#pragma unroll
                for (int j = 0; j < 8; j++) v[j] = 0.0f;
            }
            U48 a;
            a.u = make_uint4(pack2(v[0], v[1]), pack2(v[2], v[3]),
                             pack2(v[4], v[5]), pack2(v[6], v[7]));
#pragma unroll
            for (int ct = 0; ct < 4; ct++)
                acc[rf][ct] = __builtin_amdgcn_mfma_f32_16x16x32_bf16(a.s, b[ks][ct], acc[rf][ct], 0, 0, 0);
        }
    }

    unsigned short* Hs = (unsigned short*)Hb;
#pragma unroll
    for (int rf = 0; rf < 2; rf++)
#pragma unroll
        for (int ct = 0; ct < 4; ct++) {
            int col = wc * 64 + ct * 16 + lrow;
            int rbase = row_base + rf * 16 + ((lane >> 4) << 2);
#pragma unroll
            for (int r = 0; r < 4; r++) {
                int row = rbase + r;
                if (row < NN) Hs[(size_t)row * 128 + col] = f2bf(acc[rf][ct][r]);
            }
        }
}

// layer-3: A = relu(bn(Xb bf16)), out bf16 [N][40]
__global__ __launch_bounds__(256) void gemm40_mfma(const unsigned* __restrict__ Xb,
                                                   const unsigned* __restrict__ Wf,
                                                   const float* __restrict__ scsh,
                                                   unsigned* __restrict__ H3) {
    int t = threadIdx.x;
    int lane = t & 63, w = t >> 6;
    int row_base = blockIdx.x * 64 + w * 16;

    s16x8 b[4][3];
    const uint4* Wv = (const uint4*)Wf;
#pragma unroll
    for (int ks = 0; ks < 4; ks++)
#pragma unroll
        for (int ct = 0; ct < 3; ct++) {
            U48 u; u.u = Wv[(ks * 3 + ct) * 64 + lane];
            b[ks][ct] = u.s;
        }

    f32x4 acc[3] = {};
    int lrow = lane & 15;
    int koff = (lane >> 4) << 3;

#pragma unroll
    for (int ks = 0; ks < 4; ks++) {
        int k0 = ks * 32 + koff;
        float4 s0 = *(const float4*)&scsh[k0];
        float4 s1 = *(const float4*)&scsh[k0 + 4];
        float4 h0 = *(const float4*)&scsh[128 + k0];
        float4 h1 = *(const float4*)&scsh[128 + k0 + 4];
        float sc[8] = {s0.x,s0.y,s0.z,s0.w,s1.x,s1.y,s1.z,s1.w};
        float sh[8] = {h0.x,h0.y,h0.z,h0.w,h1.x,h1.y,h1.z,h1.w};
        int row = row_base + lrow;
        float v[8];
        if (row < NN) {
            uint4 u = *(const uint4*)&Xb[(size_t)row * 64 + k0 / 2];
            float av[8] = {bflo(u.x), bfhi(u.x), bflo(u.y), bfhi(u.y),
                           bflo(u.z), bfhi(u.z), bflo(u.w), bfhi(u.w)};
#pragma unroll
            for (int j = 0; j < 8; j++)
                v[j] = fmaxf(fmaf(av[j], sc[j], sh[j]), 0.0f);
        } else {
#pragma unroll
            for (int j = 0; j < 8; j++) v[j] = 0.0f;
        }
        U48 a;
        a.u = make_uint4(pack2(v[0], v[1]), pack2(v[2], v[3]),
                         pack2(v[4], v[5]), pack2(v[6], v[7]));
#pragma unroll
        for (int ct = 0; ct < 3; ct++)
            acc[ct] = __builtin_amdgcn_mfma_f32_16x16x32_bf16(a.s, b[ks][ct], acc[ct], 0, 0, 0);
    }

    unsigned short* Hs = (unsigned short*)H3;
#pragma unroll
    for (int ct = 0; ct < 3; ct++) {
        int col = ct * 16 + lrow;
        if (col >= CLS) continue;
        int rbase = row_base + ((lane >> 4) << 2);
#pragma unroll
        for (int r = 0; r < 4; r++) {
            int row = rbase + r;
            if (row < NN) Hs[(size_t)row * CLS + col] = f2bf(acc[ct][r]);
        }
    }
}

// ---------------- aggregation ----------------

// dual-node wave: each wave handles nodes (n0, n0+1) with interleaved gather streams.
// lane = feature pair. Output bf16 (post-bias).
__global__ __launch_bounds__(256) void agg128_dual(const unsigned* __restrict__ h,
                                                   const int* __restrict__ row_ptr,
                                                   const int2* __restrict__ csr,
                                                   const float* __restrict__ dinv,
                                                   const float* __restrict__ bias,
                                                   unsigned* __restrict__ outb) {
    int wid = threadIdx.x >> 6;
    int lane = threadIdx.x & 63;
    int n0 = blockIdx.x * 8 + wid * 2;     // n0, n0+1

    float d0 = dinv[n0], d1 = dinv[n0 + 1];
    float c0 = d0 * d0, c1 = d1 * d1;
    unsigned v0 = h[(size_t)n0 * 64 + lane];
    unsigned v1 = h[(size_t)(n0 + 1) * 64 + lane];
    float a00 = bflo(v0) * c0, a01 = bfhi(v0) * c0;
    float a10 = bflo(v1) * c1, a11 = bfhi(v1) * c1;

    int eA = row_ptr[n0];
    int endA = row_ptr[n0 + 1];
    int eB = endA;
    int endB = row_ptr[n0 + 2];

    // joint loop: 4 edges of each node in flight (8 gathers)
    while (eA + 4 <= endA && eB + 4 <= endB) {
        int2 pa0 = csr[eA], pa1 = csr[eA + 1], pa2 = csr[eA + 2], pa3 = csr[eA + 3];
        int2 pb0 = csr[eB], pb1 = csr[eB + 1], pb2 = csr[eB + 2], pb3 = csr[eB + 3];
        unsigned ga0 = h[(size_t)pa0.x * 64 + lane];
        unsigned ga1 = h[(size_t)pa1.x * 64 + lane];
        unsigned ga2 = h[(size_t)pa2.x * 64 + lane];
        unsigned ga3 = h[(size_t)pa3.x * 64 + lane];
        unsigned gb0 = h[(size_t)pb0.x * 64 + lane];
        unsigned gb1 = h[(size_t)pb1.x * 64 + lane];
        unsigned gb2 = h[(size_t)pb2.x * 64 + lane];
        unsigned gb3 = h[(size_t)pb3.x * 64 + lane];
        float qa0 = __int_as_float(pa0.y), qa1 = __int_as_float(pa1.y);
        float qa2 = __int_as_float(pa2.y), qa3 = __int_as_float(pa3.y);
        float qb0 = __int_as_float(pb0.y), qb1 = __int_as_float(pb1.y);
        float qb2 = __int_as_float(pb2.y), qb3 = __int_as_float(pb3.y);
        a00 = fmaf(bflo(ga0), qa0, a00); a01 = fmaf(bfhi(ga0), qa0, a01);
        a00 = fmaf(bflo(ga1), qa1, a00); a01 = fmaf(bfhi(ga1), qa1, a01);
        a00 = fmaf(bflo(ga2), qa2, a00); a01 = fmaf(bfhi(ga2), qa2, a01);
        a00 = fmaf(bflo(ga3), qa3, a00); a01 = fmaf(bfhi(ga3), qa3, a01);
        a10 = fmaf(bflo(gb0), qb0, a10); a11 = fmaf(bfhi(gb0), qb0, a11);
        a10 = fmaf(bflo(gb1), qb1, a10); a11 = fmaf(bfhi(gb1), qb1, a11);
        a10 = fmaf(bflo(gb2), qb2, a10); a11 = fmaf(bfhi(gb2), qb2, a11);
        a10 = fmaf(bflo(gb3), qb3, a10); a11 = fmaf(bfhi(gb3), qb3, a11);
        eA += 4; eB += 4;
    }
    // drain A
    for (; eA + 4 <= endA; eA += 4) {
        int2 p0 = csr[eA], p1 = csr[eA + 1], p2 = csr[eA + 2], p3 = csr[eA + 3];
        unsigned g0 = h[(size_t)p0.x * 64 + lane];
        unsigned g1 = h[(size_t)p1.x * 64 + lane];
        unsigned g2 = h[(size_t)p2.x * 64 + lane];
        unsigned g3 = h[(size_t)p3.x * 64 + lane];
        float q0 = __int_as_float(p0.y), q1 = __int_as_float(p1.y);
        float q2 = __int_as_float(p2.y), q3 = __int_as_float(p3.y);
        a00 = fmaf(bflo(g0), q0, a00); a01 = fmaf(bfhi(g0), q0, a01);
        a00 = fmaf(bflo(g1), q1, a00); a01 = fmaf(bfhi(g1), q1, a01);
        a00 = fmaf(bflo(g2), q2, a00); a01 = fmaf(bfhi(g2), q2, a01);
        a00 = fmaf(bflo(g3), q3, a00); a01 = fmaf(bfhi(g3), q3, a01);
    }
    for (; eA < endA; ++eA) {
        int2 p = csr[eA];
        float q = __int_as_float(p.y);
        unsigned g = h[(size_t)p.x * 64 + lane];
        a00 = fmaf(bflo(g), q, a00);
        a01 = fmaf(bfhi(g), q, a01);
    }
    // drain B
    for (; eB + 4 <= endB; eB += 4) {
        int2 p0 = csr[eB], p1 = csr[eB + 1], p2 = csr[eB + 2], p3 = csr[eB + 3];
        unsigned g0 = h[(size_t)p0.x * 64 + lane];
        unsigned g1 = h[(size_t)p1.x * 64 + lane];
        unsigned g2 = h[(size_t)p2.x * 64 + lane];
        unsigned g3 = h[(size_t)p3.x * 64 + lane];
        float q0 = __int_as_float(p0.y), q1 = __int_as_float(p1.y);
        float q2 = __int_as_float(p2.y), q3 = __int_as_float(p3.y);
        a10 = fmaf(bflo(g0), q0, a10); a11 = fmaf(bfhi(g0), q0, a11);
        a10 = fmaf(bflo(g1), q1, a10); a11 = fmaf(bfhi(g1), q1, a11);
        a10 = fmaf(bflo(g2), q2, a10); a11 = fmaf(bfhi(g2), q2, a11);
        a10 = fmaf(bflo(g3), q3, a10); a11 = fmaf(bfhi(g3), q3, a11);
    }
    for (; eB < endB; ++eB) {
        int2 p = csr[eB];
        float q = __int_as_float(p.y);
        unsigned g = h[(size_t)p.x * 64 + lane];
        a10 = fmaf(bflo(g), q, a10);
        a11 = fmaf(bfhi(g), q, a11);
    }

    float2 b = *(const float2*)&bias[lane * 2];
    outb[(size_t)n0 * 64 + lane]       = pack2(a00 + b.x, a01 + b.y);
    outb[(size_t)(n0 + 1) * 64 + lane] = pack2(a10 + b.x, a11 + b.y);
}

// layer-3: 3-slot layout — lane = slot*20 + fp; one gather covers 3 edges (60 lanes)
__global__ __launch_bounds__(256) void agg40_lsm(const unsigned* __restrict__ h3,
                                                 const int* __restrict__ row_ptr,
                                                 const int2* __restrict__ csr,
                                                 const float* __restrict__ dinv,
                                                 const float* __restrict__ b3,
                                                 float* __restrict__ out) {
    int wid = threadIdx.x >> 6;
    int lane = threadIdx.x & 63;
    int slot = lane / 20;
    int fp = lane - slot * 20;
    bool slot_ok = slot < 3;
    int node = blockIdx.x * 4 + wid;
    float di = dinv[node];
    float c0 = di * di;
    float a0 = 0.0f, a1 = 0.0f;
    if (slot == 0) {
        unsigned v = h3[(size_t)node * 20 + fp];
        a0 = bflo(v) * c0;
        a1 = bfhi(v) * c0;
    }
    int beg = row_ptr[node], end = row_ptr[node + 1];
    int e = beg;
    for (; e + 12 <= end; e += 12) {
        int2 p0 = csr[e + slot];
        int2 p1 = csr[e + 3 + slot];
        int2 p2 = csr[e + 6 + slot];
        int2 p3 = csr[e + 9 + slot];
        unsigned g0 = h3[(size_t)p0.x * 20 + fp];
        unsigned g1 = h3[(size_t)p1.x * 20 + fp];
        unsigned g2 = h3[(size_t)p2.x * 20 + fp];
        unsigned g3 = h3[(size_t)p3.x * 20 + fp];
        float q0 = __int_as_float(p0.y), q1 = __int_as_float(p1.y);
        float q2 = __int_as_float(p2.y), q3 = __int_as_float(p3.y);
        a0 = fmaf(bflo(g0), q0, a0); a1 = fmaf(bfhi(g0), q0, a1);
        a0 = fmaf(bflo(g1), q1, a0); a1 = fmaf(bfhi(g1), q1, a1);
        a0 = fmaf(bflo(g2), q2, a0); a1 = fmaf(bfhi(g2), q2, a1);
        a0 = fmaf(bflo(g3), q3, a0); a1 = fmaf(bfhi(g3), q3, a1);
    }
    for (; e < end; e += 3) {
        int idx = e + slot;
        bool act = slot_ok && (idx < end);
        int2 p = csr[act ? idx : (end - 1)];
        float q = act ? __int_as_float(p.y) : 0.0f;
        unsigned g = h3[(size_t)p.x * 20 + fp];
        a0 = fmaf(bflo(g), q, a0);
        a1 = fmaf(bfhi(g), q, a1);
    }
    float s1a = __shfl(a0, lane + 20), s1b = __shfl(a1, lane + 20);
    float s2a = __shfl(a0, lane + 40), s2b = __shfl(a1, lane + 40);
    bool fin = lane < 20;
    float l0 = 0.0f, l1 = 0.0f;
    if (fin) {
        float2 b = *(const float2*)&b3[lane * 2];
        l0 = a0 + s1a + s2a + b.x;
        l1 = a1 + s1b + s2b + b.y;
    }
    float m = fin ? fmaxf(l0, l1) : -1e30f;
#pragma unroll
    for (int off = 32; off > 0; off >>= 1) m = fmaxf(m, __shfl_xor(m, off));
    float s = fin ? (expf(l0 - m) + expf(l1 - m)) : 0.0f;
#pragma unroll
    for (int off = 32; off > 0; off >>= 1) s += __shfl_xor(s, off);
    float lse = m + logf(s);
    if (fin) *(float2*)&out[(size_t)node * CLS + lane * 2] = make_float2(l0 - lse, l1 - lse);
}

// ---------------- batchnorm stats (bf16 input) ----------------

__global__ __launch_bounds__(128) void bn_stats(const unsigned* __restrict__ a,
                                                float* __restrict__ stats, int n) {
    int f = threadIdx.x;          // feature 0..127
    int wrd = f >> 1;
    int hi = f & 1;
    float s = 0.0f, s2 = 0.0f;
    for (int i = blockIdx.x; i < n; i += gridDim.x) {
        unsigned v = a[(size_t)i * 64 + wrd];
        float x = hi ? bfhi(v) : bflo(v);
        s += x;
        s2 = fmaf(x, x, s2);
    }
    atomicAdd(&stats[f], s);
    atomicAdd(&stats[128 + f], s2);
}

__global__ void finalize_scsh(const float* __restrict__ stats, const float* __restrict__ g,
                              const float* __restrict__ be, float* __restrict__ scsh) {
    int f = threadIdx.x;   // 128 threads
    float mean = stats[f] * (1.0f / (float)NN);
    float var = stats[128 + f] * (1.0f / (float)NN) - mean * mean;
    float sc = g[f] * rsqrtf(var + EPSBN);
    scsh[f] = sc;
    scsh[128 + f] = be[f] - mean * sc;
}

// ---------------- launcher ----------------

extern "C" void kernel_launch(void* const* d_in, const int* in_sizes, int n_in,
                              void* d_out, int out_size, void* d_ws, size_t ws_size,
                              hipStream_t stream) {
    const float* x   = (const float*)d_in[0];
    const int*   ei  = (const int*)d_in[1];
    const float* W1  = (const float*)d_in[2];
    const float* b1  = (const float*)d_in[3];
    const float* g1  = (const float*)d_in[4];
    const float* be1 = (const float*)d_in[5];
    const float* W2  = (const float*)d_in[6];
    const float* b2  = (const float*)d_in[7];
    const float* g2  = (const float*)d_in[8];
    const float* be2 = (const float*)d_in[9];
    const float* W3  = (const float*)d_in[10];
    const float* b3  = (const float*)d_in[11];
    float* out = (float*)d_out;

    const int* src = ei;
    const int* dst = ei + EE;

    char* w = (char*)d_ws;
    size_t off = 0;
    auto alloc = [&](size_t bytes) {
        void* p = w + off;
        off += (bytes + 255) & ~(size_t)255;
        return p;
    };
    float* dinv      = (float*)alloc((size_t)NN * 4);
    int*   row_ptr   = (int*)alloc((size_t)(NN + 1) * 4);
    int*   gcur      = (int*)alloc((size_t)NBUK * 4);
    int*   gbase     = (int*)alloc((size_t)(NBUK + 1) * 4);
    int*   tmp       = (int*)alloc((size_t)NBUK * CAP * 4);   // 9.6 MB
    int2*  csr       = (int2*)alloc((size_t)EE * 8);
    float* stats1    = (float*)alloc(256 * 4);
    float* stats2    = (float*)alloc(256 * 4);
    float* scsh      = (float*)alloc(256 * 4);
    unsigned* Wf1    = (unsigned*)alloc(8192 * 4);
    unsigned* Wf2    = (unsigned*)alloc(8192 * 4);
    unsigned* Wf3    = (unsigned*)alloc(3072 * 4);
    unsigned* aH     = (unsigned*)alloc((size_t)NN * 64 * 4); // bf16 agg output (post-bias)
    unsigned* hB     = (unsigned*)alloc((size_t)NN * 64 * 4); // bf16 gemm output / gather table
    unsigned* h3     = (unsigned*)alloc((size_t)NN * 20 * 4); // bf16 h3 (pairs)

    const int NB_P1 = (EE + EPB - 1) / EPB;   // 391
    const int NB_G  = (NN + 63) / 64;

    // ---- CSR build + weight prep ----
    init_misc<<<2, 256, 0, stream>>>(gcur, stats1, stats2);
    fill_p1_binned<<<NB_P1, 256, 0, stream>>>(src, dst, gcur, tmp);
    bucket_scan<<<1, 512, 0, stream>>>(gcur, gbase, row_ptr);
    fill_p2a<<<NBUK, 256, 0, stream>>>(tmp, gcur, gbase, dinv, row_ptr);
    fill_p2b<<<NBUK, 256, 0, stream>>>(tmp, gcur, dinv, row_ptr, csr);
    prep_w128<<<32, 256, 0, stream>>>(W1, Wf1);
    prep_w128<<<32, 256, 0, stream>>>(W2, Wf2);
    prep_w40<<<12, 256, 0, stream>>>(W3, Wf3);

    // ---- layer 1 ----
    gemm128_mfma<0><<<NB_G, 256, 0, stream>>>(x, nullptr, Wf1, nullptr, nullptr, hB);
    agg128_dual<<<NN / 8, 256, 0, stream>>>(hB, row_ptr, csr, dinv, b1, aH);
    bn_stats<<<512, 128, 0, stream>>>(aH, stats1, NN);
    finalize_scsh<<<1, 128, 0, stream>>>(stats1, g1, be1, scsh);

    // ---- layer 2 (BN1 + residual + relu fused into A-fragment load) ----
    gemm128_mfma<1><<<NB_G, 256, 0, stream>>>(nullptr, aH, Wf2, scsh, x, hB);
    agg128_dual<<<NN / 8, 256, 0, stream>>>(hB, row_ptr, csr, dinv, b2, aH);
    bn_stats<<<512, 128, 0, stream>>>(aH, stats2, NN);
    finalize_scsh<<<1, 128, 0, stream>>>(stats2, g2, be2, scsh);

    // ---- layer 3 (BN2 + relu fused into A-fragment load) ----
    gemm40_mfma<<<NB_G, 256, 0, stream>>>(aH, Wf3, scsh, h3);
    agg40_lsm<<<NN / 4, 256, 0, stream>>>(h3, row_ptr, csr, dinv, b3, out);
}

// Round 8
// 439.327 us; speedup vs baseline: 1.4847x; 1.0109x over previous
//
#include <hip/hip_runtime.h>
#include <hip/hip_bf16.h>

#define NN 100000
#define EE 1600000
#define HID 128
#define CLS 40
#define EPSBN 1e-5f
#define NBUK ((NN + 255) >> 8)     // 391 buckets of 256 nodes
#define CAP 6144                   // slots per bucket region
#define EPB 4096                   // edges per p1 block
#define SRCB 13                    // src locality buckets (src>>13, 8192 rows = 2MB bf16)

typedef float f32x4 __attribute__((ext_vector_type(4)));
typedef short s16x8 __attribute__((ext_vector_type(8)));
union U48 { uint4 u; s16x8 s; };

static __device__ __forceinline__ unsigned short f2bf(float f) {
    unsigned u = __float_as_uint(f);
    unsigned r = (u + 0x7fff + ((u >> 16) & 1)) >> 16;   // RNE
    return (unsigned short)r;
}
static __device__ __forceinline__ unsigned pack2(float a, float b) {
    return (unsigned)f2bf(a) | ((unsigned)f2bf(b) << 16);
}
static __device__ __forceinline__ float bflo(unsigned v) { return __uint_as_float(v << 16); }
static __device__ __forceinline__ float bfhi(unsigned v) { return __uint_as_float(v & 0xffff0000u); }

// ---------------- combined init + W pre-pack ----------------
// blocks 0-31: W1 frags; 32-63: W2 frags; 64-75: W3 frags; 76-77: gcur/stats init
__global__ void prep_all(const float* __restrict__ W1, const float* __restrict__ W2,
                         const float* __restrict__ W3,
                         unsigned* __restrict__ Wf1, unsigned* __restrict__ Wf2,
                         unsigned* __restrict__ Wf3,
                         int* gcur, float* stats1, float* stats2) {
    int blk = blockIdx.x;
    int tid = threadIdx.x;
    if (blk < 64) {
        const float* W = (blk < 32) ? W1 : W2;
        unsigned* Wf = (blk < 32) ? Wf1 : Wf2;
        int t = ((blk & 31) << 8) + tid;          // < 8192
        int q = t & 3, lane = (t >> 2) & 63, f = t >> 8;
        int ks = f >> 3, ct = f & 7;
        int k = ks * 32 + ((lane >> 4) << 3) + q * 2;
        int col = ct * 16 + (lane & 15);
        Wf[t] = pack2(W[k * 128 + col], W[(k + 1) * 128 + col]);
    } else if (blk < 76) {
        int t = ((blk - 64) << 8) + tid;          // < 3072
        int q = t & 3, lane = (t >> 2) & 63, f = t >> 8;
        int ks = f / 3, ct = f - ks * 3;
        int k = ks * 32 + ((lane >> 4) << 3) + q * 2;
        int col = ct * 16 + (lane & 15);
        float v0 = (col < CLS) ? W3[k * CLS + col] : 0.0f;
        float v1 = (col < CLS) ? W3[(k + 1) * CLS + col] : 0.0f;
        Wf3[t] = pack2(v0, v1);
    } else {
        int j = ((blk - 76) << 8) + tid;
        if (j < NBUK) gcur[j] = j * CAP;
        if (blk == 76) {
            stats1[tid] = 0.0f;
            stats2[tid] = 0.0f;
        }
    }
}

// ---------------- CSR build (LDS-binned, block-private write runs) ----------------

__global__ __launch_bounds__(256) void fill_p1_binned(const int* __restrict__ src,
                                                      const int* __restrict__ dst,
                                                      int* gcur, int* __restrict__ tmp) {
    __shared__ int cnt[NBUK];
    __shared__ int base[NBUK];
    int tid = threadIdx.x;
    for (int j = tid; j < NBUK; j += 256) cnt[j] = 0;
    __syncthreads();

    int es[16], ed[16];
    int i0 = blockIdx.x * EPB;
#pragma unroll
    for (int k = 0; k < 16; k++) {
        int i = i0 + k * 256 + tid;
        bool ok = i < EE;
        es[k] = ok ? src[i] : -1;
        ed[k] = ok ? dst[i] : 0;
        if (ok) atomicAdd(&cnt[ed[k] >> 8], 1);
    }
    __syncthreads();
    for (int j = tid; j < NBUK; j += 256) {
        int c = cnt[j];
        base[j] = c ? atomicAdd(&gcur[j], c) : 0;
        cnt[j] = 0;
    }
    __syncthreads();
#pragma unroll
    for (int k = 0; k < 16; k++) {
        if (es[k] >= 0) {
            int b = ed[k] >> 8;
            int r = atomicAdd(&cnt[b], 1);
            tmp[base[b] + r] = (es[k] << 8) | (ed[k] & 255);
        }
    }
}

__global__ __launch_bounds__(512) void bucket_scan(const int* __restrict__ gcur,
                                                   int* __restrict__ gbase,
                                                   int* __restrict__ row_ptr) {
    __shared__ int sc[512];
    int tid = threadIdx.x;
    int v = (tid < NBUK) ? gcur[tid] - tid * CAP : 0;
    sc[tid] = v;
    __syncthreads();
    for (int off = 1; off < 512; off <<= 1) {
        int t = (tid >= off) ? sc[tid - off] : 0;
        __syncthreads();
        sc[tid] += t;
        __syncthreads();
    }
    if (tid < NBUK) gbase[tid] = sc[tid] - v;
    if (tid == NBUK - 1) {
        gbase[NBUK] = sc[tid];
        row_ptr[NN] = sc[tid];
    }
}

// phase 2a: per-(node, src-bucket) histogram -> dinv + row_ptr
__global__ __launch_bounds__(256) void fill_p2a(const int* __restrict__ tmp,
                                                const int* __restrict__ gcur,
                                                const int* __restrict__ gbase,
                                                float* __restrict__ dinv,
                                                int* __restrict__ row_ptr) {
    __shared__ int cnt[256 * SRCB];
    __shared__ int sc[256];
    int b = blockIdx.x;
    int tid = threadIdx.x;
    int total = gcur[b] - b * CAP;
    for (int j = tid; j < 256 * SRCB; j += 256) cnt[j] = 0;
    __syncthreads();
    int lo = b * CAP;
    for (int k = tid; k < total; k += 256) {
        int v = tmp[lo + k];
        int dl = v & 255;
        int s = ((unsigned)v) >> 8;
        atomicAdd(&cnt[dl * SRCB + (s >> 13)], 1);
    }
    __syncthreads();
    int c = 0;
#pragma unroll
    for (int j = 0; j < SRCB; j++) c += cnt[tid * SRCB + j];
    sc[tid] = c;
    __syncthreads();
    for (int off = 1; off < 256; off <<= 1) {
        int t = (tid >= off) ? sc[tid - off] : 0;
        __syncthreads();
        sc[tid] += t;
        __syncthreads();
    }
    int node = (b << 8) + tid;
    if (node < NN) {
        dinv[node] = rsqrtf((float)(c + 1));   // +1 self loop
        row_ptr[node] = gbase[b] + sc[tid] - c;
    }
}

// phase 2b: ranked scatter ordered by (node, src-bucket) -> L2-friendly gather order
__global__ __launch_bounds__(256) void fill_p2b(const int* __restrict__ tmp,
                                                const int* __restrict__ gcur,
                                                const float* __restrict__ dinv,
                                                const int* __restrict__ row_ptr,
                                                int2* __restrict__ csr) {
    __shared__ int cur[256 * SRCB];
    __shared__ float dlv[256];
    int b = blockIdx.x;
    int tid = threadIdx.x;
    int total = gcur[b] - b * CAP;
    int node = (b << 8) + tid;
    dlv[tid] = (node < NN) ? dinv[node] : 0.0f;
    for (int j = tid; j < 256 * SRCB; j += 256) cur[j] = 0;
    __syncthreads();
    int lo = b * CAP;
    for (int k = tid; k < total; k += 256) {
        int v = tmp[lo + k];
        int dl = v & 255;
        int s = ((unsigned)v) >> 8;
        atomicAdd(&cur[dl * SRCB + (s >> 13)], 1);
    }
    __syncthreads();
    if (node < NN) {
        int base = row_ptr[node];
#pragma unroll
        for (int j = 0; j < SRCB; j++) {
            int t = cur[tid * SRCB + j];
            cur[tid * SRCB + j] = base;
            base += t;
        }
    }
    __syncthreads();
    for (int k = tid; k < total; k += 256) {
        int v = tmp[lo + k];
        int dl = v & 255;
        int s = ((unsigned)v) >> 8;
        int p = atomicAdd(&cur[dl * SRCB + (s >> 13)], 1);
        csr[p] = make_int2(s, __float_as_int(dinv[s] * dlv[dl]));
    }
}

// ---------------- MFMA GEMMs ----------------

// MODE 0: A = Xf (fp32). MODE 1: A = relu(bn(Xb bf16) + xres fp32). Out bf16 H [N][128].
template <int MODE>
__global__ __launch_bounds__(256) void gemm128_mfma(const float* __restrict__ Xf,
                                                    const unsigned* __restrict__ Xb,
                                                    const unsigned* __restrict__ Wf,
                                                    const float* __restrict__ scsh,
                                                    const float* __restrict__ xres,
                                                    unsigned* __restrict__ Hb) {
    int t = threadIdx.x;
    int lane = t & 63, w = t >> 6;
    int wr = w >> 1, wc = w & 1;
    int row_base = blockIdx.x * 64 + wr * 32;

    s16x8 b[4][4];
    const uint4* Wv = (const uint4*)Wf;
#pragma unroll
    for (int ks = 0; ks < 4; ks++)
#pragma unroll
        for (int ct = 0; ct < 4; ct++) {
            int f = ks * 8 + wc * 4 + ct;
            U48 u; u.u = Wv[f * 64 + lane];
            b[ks][ct] = u.s;
        }

    f32x4 acc[2][4] = {};
    int lrow = lane & 15;
    int koff = (lane >> 4) << 3;

#pragma unroll
    for (int ks = 0; ks < 4; ks++) {
        int k0 = ks * 32 + koff;
        float sc[8], sh[8];
        if (MODE == 1) {
            float4 s0 = *(const float4*)&scsh[k0];
            float4 s1 = *(const float4*)&scsh[k0 + 4];
            float4 h0 = *(const float4*)&scsh[128 + k0];
            float4 h1 = *(const float4*)&scsh[128 + k0 + 4];
            sc[0]=s0.x; sc[1]=s0.y; sc[2]=s0.z; sc[3]=s0.w;
            sc[4]=s1.x; sc[5]=s1.y; sc[6]=s1.z; sc[7]=s1.w;
            sh[0]=h0.x; sh[1]=h0.y; sh[2]=h0.z; sh[3]=h0.w;
            sh[4]=h1.x; sh[5]=h1.y; sh[6]=h1.z; sh[7]=h1.w;
        }
#pragma unroll
        for (int rf = 0; rf < 2; rf++) {
            int row = row_base + rf * 16 + lrow;
            float v[8];
            if (row < NN) {
                if (MODE == 0) {
                    float4 a0 = *(const float4*)&Xf[(size_t)row * 128 + k0];
                    float4 a1 = *(const float4*)&Xf[(size_t)row * 128 + k0 + 4];
                    v[0]=a0.x; v[1]=a0.y; v[2]=a0.z; v[3]=a0.w;
                    v[4]=a1.x; v[5]=a1.y; v[6]=a1.z; v[7]=a1.w;
                } else {
                    uint4 u = *(const uint4*)&Xb[(size_t)row * 64 + k0 / 2];
                    v[0]=bflo(u.x); v[1]=bfhi(u.x); v[2]=bflo(u.y); v[3]=bfhi(u.y);
                    v[4]=bflo(u.z); v[5]=bfhi(u.z); v[6]=bflo(u.w); v[7]=bfhi(u.w);
                    float4 r0 = *(const float4*)&xres[(size_t)row * 128 + k0];
                    float4 r1 = *(const float4*)&xres[(size_t)row * 128 + k0 + 4];
                    float rr[8] = {r0.x,r0.y,r0.z,r0.w,r1.x,r1.y,r1.z,r1.w};
#pragma unroll
                    for (int j = 0; j < 8; j++)
                        v[j] = fmaxf(fmaf(v[j], sc[j], sh[j]) + rr[j], 0.0f);
                }
            } else {
#pragma unroll
                for (int j = 0; j < 8; j++) v[j] = 0.0f;
            }
            U48 a;
            a.u = make_uint4(pack2(v[0], v[1]), pack2(v[2], v[3]),
                             pack2(v[4], v[5]), pack2(v[6], v[7]));
#pragma unroll
            for (int ct = 0; ct < 4; ct++)
                acc[rf][ct] = __builtin_amdgcn_mfma_f32_16x16x32_bf16(a.s, b[ks][ct], acc[rf][ct], 0, 0, 0);
        }
    }

    unsigned short* Hs = (unsigned short*)Hb;
#pragma unroll
    for (int rf = 0; rf < 2; rf++)
#pragma unroll
        for (int ct = 0; ct < 4; ct++) {
            int col = wc * 64 + ct * 16 + lrow;
            int rbase = row_base + rf * 16 + ((lane >> 4) << 2);
#pragma unroll
            for (int r = 0; r < 4; r++) {
                int row = rbase + r;
                if (row < NN) Hs[(size_t)row * 128 + col] = f2bf(acc[rf][ct][r]);
            }
        }
}

// layer-3: A = relu(bn(Xb bf16)), out bf16 [N][40]
__global__ __launch_bounds__(256) void gemm40_mfma(const unsigned* __restrict__ Xb,
                                                   const unsigned* __restrict__ Wf,
                                                   const float* __restrict__ scsh,
                                                   unsigned* __restrict__ H3) {
    int t = threadIdx.x;
    int lane = t & 63, w = t >> 6;
    int row_base = blockIdx.x * 64 + w * 16;

    s16x8 b[4][3];
    const uint4* Wv = (const uint4*)Wf;
#pragma unroll
    for (int ks = 0; ks < 4; ks++)
#pragma unroll
        for (int ct = 0; ct < 3; ct++) {
            U48 u; u.u = Wv[(ks * 3 + ct) * 64 + lane];
            b[ks][ct] = u.s;
        }

    f32x4 acc[3] = {};
    int lrow = lane & 15;
    int koff = (lane >> 4) << 3;

#pragma unroll
    for (int ks = 0; ks < 4; ks++) {
        int k0 = ks * 32 + koff;
        float4 s0 = *(const float4*)&scsh[k0];
        float4 s1 = *(const float4*)&scsh[k0 + 4];
        float4 h0 = *(const float4*)&scsh[128 + k0];
        float4 h1 = *(const float4*)&scsh[128 + k0 + 4];
        float sc[8] = {s0.x,s0.y,s0.z,s0.w,s1.x,s1.y,s1.z,s1.w};
        float sh[8] = {h0.x,h0.y,h0.z,h0.w,h1.x,h1.y,h1.z,h1.w};
        int row = row_base + lrow;
        float v[8];
        if (row < NN) {
            uint4 u = *(const uint4*)&Xb[(size_t)row * 64 + k0 / 2];
            float av[8] = {bflo(u.x), bfhi(u.x), bflo(u.y), bfhi(u.y),
                           bflo(u.z), bfhi(u.z), bflo(u.w), bfhi(u.w)};
#pragma unroll
            for (int j = 0; j < 8; j++)
                v[j] = fmaxf(fmaf(av[j], sc[j], sh[j]), 0.0f);
        } else {
#pragma unroll
            for (int j = 0; j < 8; j++) v[j] = 0.0f;
        }
        U48 a;
        a.u = make_uint4(pack2(v[0], v[1]), pack2(v[2], v[3]),
                         pack2(v[4], v[5]), pack2(v[6], v[7]));
#pragma unroll
        for (int ct = 0; ct < 3; ct++)
            acc[ct] = __builtin_amdgcn_mfma_f32_16x16x32_bf16(a.s, b[ks][ct], acc[ct], 0, 0, 0);
    }

    unsigned short* Hs = (unsigned short*)H3;
#pragma unroll
    for (int ct = 0; ct < 3; ct++) {
        int col = ct * 16 + lrow;
        if (col >= CLS) continue;
        int rbase = row_base + ((lane >> 4) << 2);
#pragma unroll
        for (int r = 0; r < 4; r++) {
            int row = rbase + r;
            if (row < NN) Hs[(size_t)row * CLS + col] = f2bf(acc[ct][r]);
        }
    }
}

// ---------------- aggregation ----------------

// dual-node wave: nodes (n0, n0+1), interleaved gather streams, bf16 out
__global__ __launch_bounds__(256) void agg128_dual(const unsigned* __restrict__ h,
                                                   const int* __restrict__ row_ptr,
                                                   const int2* __restrict__ csr,
                                                   const float* __restrict__ dinv,
                                                   const float* __restrict__ bias,
                                                   unsigned* __restrict__ outb) {
    int wid = threadIdx.x >> 6;
    int lane = threadIdx.x & 63;
    int n0 = blockIdx.x * 8 + wid * 2;

    float d0 = dinv[n0], d1 = dinv[n0 + 1];
    float c0 = d0 * d0, c1 = d1 * d1;
    unsigned v0 = h[(size_t)n0 * 64 + lane];
    unsigned v1 = h[(size_t)(n0 + 1) * 64 + lane];
    float a00 = bflo(v0) * c0, a01 = bfhi(v0) * c0;
    float a10 = bflo(v1) * c1, a11 = bfhi(v1) * c1;

    int eA = row_ptr[n0];
    int endA = row_ptr[n0 + 1];
    int eB = endA;
    int endB = row_ptr[n0 + 2];

    while (eA + 4 <= endA && eB + 4 <= endB) {
        int2 pa0 = csr[eA], pa1 = csr[eA + 1], pa2 = csr[eA + 2], pa3 = csr[eA + 3];
        int2 pb0 = csr[eB], pb1 = csr[eB + 1], pb2 = csr[eB + 2], pb3 = csr[eB + 3];
        unsigned ga0 = h[(size_t)pa0.x * 64 + lane];
        unsigned ga1 = h[(size_t)pa1.x * 64 + lane];
        unsigned ga2 = h[(size_t)pa2.x * 64 + lane];
        unsigned ga3 = h[(size_t)pa3.x * 64 + lane];
        unsigned gb0 = h[(size_t)pb0.x * 64 + lane];
        unsigned gb1 = h[(size_t)pb1.x * 64 + lane];
        unsigned gb2 = h[(size_t)pb2.x * 64 + lane];
        unsigned gb3 = h[(size_t)pb3.x * 64 + lane];
        float qa0 = __int_as_float(pa0.y), qa1 = __int_as_float(pa1.y);
        float qa2 = __int_as_float(pa2.y), qa3 = __int_as_float(pa3.y);
        float qb0 = __int_as_float(pb0.y), qb1 = __int_as_float(pb1.y);
        float qb2 = __int_as_float(pb2.y), qb3 = __int_as_float(pb3.y);
        a00 = fmaf(bflo(ga0), qa0, a00); a01 = fmaf(bfhi(ga0), qa0, a01);
        a00 = fmaf(bflo(ga1), qa1, a00); a01 = fmaf(bfhi(ga1), qa1, a01);
        a00 = fmaf(bflo(ga2), qa2, a00); a01 = fmaf(bfhi(ga2), qa2, a01);
        a00 = fmaf(bflo(ga3), qa3, a00); a01 = fmaf(bfhi(ga3), qa3, a01);
        a10 = fmaf(bflo(gb0), qb0, a10); a11 = fmaf(bfhi(gb0), qb0, a11);
        a10 = fmaf(bflo(gb1), qb1, a10); a11 = fmaf(bfhi(gb1), qb1, a11);
        a10 = fmaf(bflo(gb2), qb2, a10); a11 = fmaf(bfhi(gb2), qb2, a11);
        a10 = fmaf(bflo(gb3), qb3, a10); a11 = fmaf(bfhi(gb3), qb3, a11);
        eA += 4; eB += 4;
    }
    for (; eA + 4 <= endA; eA += 4) {
        int2 p0 = csr[eA], p1 = csr[eA + 1], p2 = csr[eA + 2], p3 = csr[eA + 3];
        unsigned g0 = h[(size_t)p0.x * 64 + lane];
        unsigned g1 = h[(size_t)p1.x * 64 + lane];
        unsigned g2 = h[(size_t)p2.x * 64 + lane];
        unsigned g3 = h[(size_t)p3.x * 64 + lane];
        float q0 = __int_as_float(p0.y), q1 = __int_as_float(p1.y);
        float q2 = __int_as_float(p2.y), q3 = __int_as_float(p3.y);
        a00 = fmaf(bflo(g0), q0, a00); a01 = fmaf(bfhi(g0), q0, a01);
        a00 = fmaf(bflo(g1), q1, a00); a01 = fmaf(bfhi(g1), q1, a01);
        a00 = fmaf(bflo(g2), q2, a00); a01 = fmaf(bfhi(g2), q2, a01);
        a00 = fmaf(bflo(g3), q3, a00); a01 = fmaf(bfhi(g3), q3, a01);
    }
    for (; eA < endA; ++eA) {
        int2 p = csr[eA];
        float q = __int_as_float(p.y);
        unsigned g = h[(size_t)p.x * 64 + lane];
        a00 = fmaf(bflo(g), q, a00);
        a01 = fmaf(bfhi(g), q, a01);
    }
    for (; eB + 4 <= endB; eB += 4) {
        int2 p0 = csr[eB], p1 = csr[eB + 1], p2 = csr[eB + 2], p3 = csr[eB + 3];
        unsigned g0 = h[(size_t)p0.x * 64 + lane];
        unsigned g1 = h[(size_t)p1.x * 64 + lane];
        unsigned g2 = h[(size_t)p2.x * 64 + lane];
        unsigned g3 = h[(size_t)p3.x * 64 + lane];
        float q0 = __int_as_float(p0.y), q1 = __int_as_float(p1.y);
        float q2 = __int_as_float(p2.y), q3 = __int_as_float(p3.y);
        a10 = fmaf(bflo(g0), q0, a10); a11 = fmaf(bfhi(g0), q0, a11);
        a10 = fmaf(bflo(g1), q1, a10); a11 = fmaf(bfhi(g1), q1, a11);
        a10 = fmaf(bflo(g2), q2, a10); a11 = fmaf(bfhi(g2), q2, a11);
        a10 = fmaf(bflo(g3), q3, a10); a11 = fmaf(bfhi(g3), q3, a11);
    }
    for (; eB < endB; ++eB) {
        int2 p = csr[eB];
        float q = __int_as_float(p.y);
        unsigned g = h[(size_t)p.x * 64 + lane];
        a10 = fmaf(bflo(g), q, a10);
        a11 = fmaf(bfhi(g), q, a11);
    }

    float2 b = *(const float2*)&bias[lane * 2];
    outb[(size_t)n0 * 64 + lane]       = pack2(a00 + b.x, a01 + b.y);
    outb[(size_t)(n0 + 1) * 64 + lane] = pack2(a10 + b.x, a11 + b.y);
}

// layer-3: 3-slot layout — lane = slot*20 + fp; one gather covers 3 edges
__global__ __launch_bounds__(256) void agg40_lsm(const unsigned* __restrict__ h3,
                                                 const int* __restrict__ row_ptr,
                                                 const int2* __restrict__ csr,
                                                 const float* __restrict__ dinv,
                                                 const float* __restrict__ b3,
                                                 float* __restrict__ out) {
    int wid = threadIdx.x >> 6;
    int lane = threadIdx.x & 63;
    int slot = lane / 20;
    int fp = lane - slot * 20;
    bool slot_ok = slot < 3;
    int node = blockIdx.x * 4 + wid;
    float di = dinv[node];
    float c0 = di * di;
    float a0 = 0.0f, a1 = 0.0f;
    if (slot == 0) {
        unsigned v = h3[(size_t)node * 20 + fp];
        a0 = bflo(v) * c0;
        a1 = bfhi(v) * c0;
    }
    int beg = row_ptr[node], end = row_ptr[node + 1];
    int e = beg;
    for (; e + 12 <= end; e += 12) {
        int2 p0 = csr[e + slot];
        int2 p1 = csr[e + 3 + slot];
        int2 p2 = csr[e + 6 + slot];
        int2 p3 = csr[e + 9 + slot];
        unsigned g0 = h3[(size_t)p0.x * 20 + fp];
        unsigned g1 = h3[(size_t)p1.x * 20 + fp];
        unsigned g2 = h3[(size_t)p2.x * 20 + fp];
        unsigned g3 = h3[(size_t)p3.x * 20 + fp];
        float q0 = __int_as_float(p0.y), q1 = __int_as_float(p1.y);
        float q2 = __int_as_float(p2.y), q3 = __int_as_float(p3.y);
        a0 = fmaf(bflo(g0), q0, a0); a1 = fmaf(bfhi(g0), q0, a1);
        a0 = fmaf(bflo(g1), q1, a0); a1 = fmaf(bfhi(g1), q1, a1);
        a0 = fmaf(bflo(g2), q2, a0); a1 = fmaf(bfhi(g2), q2, a1);
        a0 = fmaf(bflo(g3), q3, a0); a1 = fmaf(bfhi(g3), q3, a1);
    }
    for (; e < end; e += 3) {
        int idx = e + slot;
        bool act = slot_ok && (idx < end);
        int2 p = csr[act ? idx : (end - 1)];
        float q = act ? __int_as_float(p.y) : 0.0f;
        unsigned g = h3[(size_t)p.x * 20 + fp];
        a0 = fmaf(bflo(g), q, a0);
        a1 = fmaf(bfhi(g), q, a1);
    }
    float s1a = __shfl(a0, lane + 20), s1b = __shfl(a1, lane + 20);
    float s2a = __shfl(a0, lane + 40), s2b = __shfl(a1, lane + 40);
    bool fin = lane < 20;
    float l0 = 0.0f, l1 = 0.0f;
    if (fin) {
        float2 b = *(const float2*)&b3[lane * 2];
        l0 = a0 + s1a + s2a + b.x;
        l1 = a1 + s1b + s2b + b.y;
    }
    float m = fin ? fmaxf(l0, l1) : -1e30f;
#pragma unroll
    for (int off = 32; off > 0; off >>= 1) m = fmaxf(m, __shfl_xor(m, off));
    float s = fin ? (expf(l0 - m) + expf(l1 - m)) : 0.0f;
#pragma unroll
    for (int off = 32; off > 0; off >>= 1) s += __shfl_xor(s, off);
    float lse = m + logf(s);
    if (fin) *(float2*)&out[(size_t)node * CLS + lane * 2] = make_float2(l0 - lse, l1 - lse);
}

// ---------------- batchnorm stats (bf16 input) ----------------

__global__ __launch_bounds__(128) void bn_stats(const unsigned* __restrict__ a,
                                                float* __restrict__ stats, int n) {
    int f = threadIdx.x;
    int wrd = f >> 1;
    int hi = f & 1;
    float s = 0.0f, s2 = 0.0f;
    for (int i = blockIdx.x; i < n; i += gridDim.x) {
        unsigned v = a[(size_t)i * 64 + wrd];
        float x = hi ? bfhi(v) : bflo(v);
        s += x;
        s2 = fmaf(x, x, s2);
    }
    atomicAdd(&stats[f], s);
    atomicAdd(&stats[128 + f], s2);
}

__global__ void finalize_scsh(const float* __restrict__ stats, const float* __restrict__ g,
                              const float* __restrict__ be, float* __restrict__ scsh) {
    int f = threadIdx.x;   // 128 threads
    float mean = stats[f] * (1.0f / (float)NN);
    float var = stats[128 + f] * (1.0f / (float)NN) - mean * mean;
    float sc = g[f] * rsqrtf(var + EPSBN);
    scsh[f] = sc;
    scsh[128 + f] = be[f] - mean * sc;
}

// ---------------- launcher ----------------

extern "C" void kernel_launch(void* const* d_in, const int* in_sizes, int n_in,
                              void* d_out, int out_size, void* d_ws, size_t ws_size,
                              hipStream_t stream) {
    const float* x   = (const float*)d_in[0];
    const int*   ei  = (const int*)d_in[1];
    const float* W1  = (const float*)d_in[2];
    const float* b1  = (const float*)d_in[3];
    const float* g1  = (const float*)d_in[4];
    const float* be1 = (const float*)d_in[5];
    const float* W2  = (const float*)d_in[6];
    const float* b2  = (const float*)d_in[7];
    const float* g2  = (const float*)d_in[8];
    const float* be2 = (const float*)d_in[9];
    const float* W3  = (const float*)d_in[10];
    const float* b3  = (const float*)d_in[11];
    float* out = (float*)d_out;

    const int* src = ei;
    const int* dst = ei + EE;

    char* w = (char*)d_ws;
    size_t off = 0;
    auto alloc = [&](size_t bytes) {
        void* p = w + off;
        off += (bytes + 255) & ~(size_t)255;
        return p;
    };
    float* dinv      = (float*)alloc((size_t)NN * 4);
    int*   row_ptr   = (int*)alloc((size_t)(NN + 1) * 4);
    int*   gcur      = (int*)alloc((size_t)NBUK * 4);
    int*   gbase     = (int*)alloc((size_t)(NBUK + 1) * 4);
    int*   tmp       = (int*)alloc((size_t)NBUK * CAP * 4);   // 9.6 MB
    int2*  csr       = (int2*)alloc((size_t)EE * 8);
    float* stats1    = (float*)alloc(256 * 4);
    float* stats2    = (float*)alloc(256 * 4);
    float* scsh      = (float*)alloc(256 * 4);
    unsigned* Wf1    = (unsigned*)alloc(8192 * 4);
    unsigned* Wf2    = (unsigned*)alloc(8192 * 4);
    unsigned* Wf3    = (unsigned*)alloc(3072 * 4);
    unsigned* aH     = (unsigned*)alloc((size_t)NN * 64 * 4); // bf16 agg output (post-bias)
    unsigned* hB     = (unsigned*)alloc((size_t)NN * 64 * 4); // bf16 gemm output / gather table
    unsigned* h3     = (unsigned*)alloc((size_t)NN * 20 * 4); // bf16 h3 (pairs)

    const int NB_P1 = (EE + EPB - 1) / EPB;   // 391
    const int NB_G  = (NN + 63) / 64;

    // ---- CSR build + weight prep ----
    prep_all<<<78, 256, 0, stream>>>(W1, W2, W3, Wf1, Wf2, Wf3, gcur, stats1, stats2);
    fill_p1_binned<<<NB_P1, 256, 0, stream>>>(src, dst, gcur, tmp);
    bucket_scan<<<1, 512, 0, stream>>>(gcur, gbase, row_ptr);
    fill_p2a<<<NBUK, 256, 0, stream>>>(tmp, gcur, gbase, dinv, row_ptr);
    fill_p2b<<<NBUK, 256, 0, stream>>>(tmp, gcur, dinv, row_ptr, csr);

    // ---- layer 1 ----
    gemm128_mfma<0><<<NB_G, 256, 0, stream>>>(x, nullptr, Wf1, nullptr, nullptr, hB);
    agg128_dual<<<NN / 8, 256, 0, stream>>>(hB, row_ptr, csr, dinv, b1, aH);
    bn_stats<<<512, 128, 0, stream>>>(aH, stats1, NN);
    finalize_scsh<<<1, 128, 0, stream>>>(stats1, g1, be1, scsh);

    // ---- layer 2 (BN1 + residual + relu fused into A-fragment load) ----
    gemm128_mfma<1><<<NB_G, 256, 0, stream>>>(nullptr, aH, Wf2, scsh, x, hB);
    agg128_dual<<<NN / 8, 256, 0, stream>>>(hB, row_ptr, csr, dinv, b2, aH);
    bn_stats<<<512, 128, 0, stream>>>(aH, stats2, NN);
    finalize_scsh<<<1, 128, 0, stream>>>(stats2, g2, be2, scsh);

    // ---- layer 3 (BN2 + relu fused into A-fragment load) ----
    gemm40_mfma<<<NB_G, 256, 0, stream>>>(aH, Wf3, scsh, h3);
    agg40_lsm<<<NN / 4, 256, 0, stream>>>(h3, row_ptr, csr, dinv, b3, out);
}